// Round 6
// baseline (752.026 us; speedup 1.0000x reference)
//
#include <hip/hip_runtime.h>
#include <hip/hip_bf16.h>

// ---------------- problem constants ----------------
#define NP     200000
#define NPOS   320
#define NT     32
#define FEAT   128
#define EMB    64
#define HID    128
#define EP2P   400000
#define EP2T   640
#define ECHEM  1000000

#define CHEM_CAP 32
#define P2P_CAP  2048
#define T2_CAP   64
#define SC_GRID  2048
#define PB_BLOCKS 64
#define AGG_SPLIT 8

typedef unsigned short u16;
typedef __attribute__((ext_vector_type(8))) short short8;   // 8 bf16 = 4 VGPRs
typedef __attribute__((ext_vector_type(4))) float f32x4;

static __device__ inline u16 f2bf(float f) {               // RNE fp32->bf16
    unsigned u = __float_as_uint(f);
    return (u16)((u + 0x7fffu + ((u >> 16) & 1u)) >> 16);
}
static __device__ inline float bf2f(u16 h) {
    return __uint_as_float(((unsigned)h) << 16);
}
static __device__ inline float bprod(unsigned a, unsigned b) {  // dot of 2 packed bf16 pairs
    float a0 = __uint_as_float(a << 16), a1 = __uint_as_float(a & 0xffff0000u);
    float b0 = __uint_as_float(b << 16), b1 = __uint_as_float(b & 0xffff0000u);
    return fmaf(a0, b0, a1 * b1);
}

// ---------------- init: counters, pos embeds, pos_agg zero, weight transpose->bf16 ----------------
// Wpack layout: W1t[128][128] | W2t[64][128] | Qt[64][64] | Kt[64][64] | Vt[64][64] | Msgt[64][64]
__global__ __launch_bounds__(256) void init_kernel(int* __restrict__ chem_cnt,
                                                   int* __restrict__ p2p_cnt,
                                                   float* __restrict__ Zp,
                                                   const int* __restrict__ pos_idx,
                                                   const float* __restrict__ pos_table,
                                                   float* __restrict__ pos0,
                                                   float* __restrict__ pos_agg,
                                                   const float* __restrict__ w1,
                                                   const float* __restrict__ w2,
                                                   const float* __restrict__ qw,
                                                   const float* __restrict__ kw,
                                                   const float* __restrict__ vw,
                                                   const float* __restrict__ mw,
                                                   u16* __restrict__ Wpack)
{
    int t = blockIdx.x * 256 + threadIdx.x;
    if (t < NP) chem_cnt[t] = 0;
    if (t < NPOS) p2p_cnt[t] = 0;
    if (t < NPOS * EMB) {
        pos0[t] = pos_table[pos_idx[t >> 6] * EMB + (t & 63)];
        pos_agg[t] = 0.f;
    }
    if (t == 0) *Zp = 0.f;
    if (t < 40960) {
        float v;
        if (t < 16384)        { int i = t;         v = w1[(i & 127) * 128 + (i >> 7)]; }
        else if (t < 24576)   { int i = t - 16384; v = w2[(i & 127) * 64  + (i >> 7)]; }
        else if (t < 28672)   { int i = t - 24576; v = qw[(i & 63) * 64 + (i >> 6)]; }
        else if (t < 32768)   { int i = t - 28672; v = kw[(i & 63) * 64 + (i >> 6)]; }
        else if (t < 36864)   { int i = t - 32768; v = vw[(i & 63) * 64 + (i >> 6)]; }
        else                  { int i = t - 36864; v = mw[(i & 63) * 64 + (i >> 6)]; }
        Wpack[t] = f2bf(v);
    }
}

// ---------------- fused MFMA encoder: X(fp32) -> h -> emb(bf16) -> Q,K,V ----------------
// 64 rows/block, wave owns 16 rows; single reused per-wave LDS buffer.
// ALL outputs staged C-layout -> LDS -> coalesced short8 (16B/lane) global stores:
// one store inst covers 8 full 128B rows (1KB), killing the partial-line write amplification.
// Per-wave DS ops are in-order, so sequential reuse of the tile needs no barriers.
__global__ __launch_bounds__(256, 8) void mfma_enc(
    const float* __restrict__ X,
    const u16* __restrict__ W1t, const u16* __restrict__ W2t,
    const u16* __restrict__ Qt,  const u16* __restrict__ Kt, const u16* __restrict__ Vt,
    const float* __restrict__ b1, const float* __restrict__ b2,
    const float* __restrict__ qbv, const float* __restrict__ kbv, const float* __restrict__ vbv,
    u16* __restrict__ emb_b,
    u16* __restrict__ Qb, u16* __restrict__ Kb, u16* __restrict__ Vb)
{
    __shared__ u16 buf[4][16 * 136];   // per-wave tile; h at stride 136, then emb/C-tiles at stride 72
    const int tid = threadIdx.x, wave = tid >> 6, lane = tid & 63;
    const int m_ = lane & 15, quad = lane >> 4;
    const int rbase = blockIdx.x * 64 + wave * 16;
    const int srow = lane >> 3;          // coalesced-store row 0..7
    const int scol = (lane & 7) * 8;     // coalesced-store col (u16 units)

    // A-fragments of X: load fp32, round to bf16 in-register
    const float4* xrow = (const float4*)(X + (size_t)(rbase + m_) * 128);
    short8 ax[4];
#pragma unroll
    for (int kk = 0; kk < 4; ++kk) {
        float4 u = xrow[kk * 8 + quad * 2];
        float4 v = xrow[kk * 8 + quad * 2 + 1];
        short8 t;
        t[0] = (short)f2bf(u.x); t[1] = (short)f2bf(u.y);
        t[2] = (short)f2bf(u.z); t[3] = (short)f2bf(u.w);
        t[4] = (short)f2bf(v.x); t[5] = (short)f2bf(v.y);
        t[6] = (short)f2bf(v.z); t[7] = (short)f2bf(v.w);
        ax[kk] = t;
    }

    u16* hrow = &buf[wave][0];
    // ---- enc1: h = relu(X @ W1 + b1), 8 col-tiles of 16 ----
#pragma unroll
    for (int n0 = 0; n0 < 8; ++n0) {
        float bv = b1[n0 * 16 + m_];
        f32x4 acc = {bv, bv, bv, bv};
        const short8* w = (const short8*)(W1t + (size_t)(n0 * 16 + m_) * 128);
#pragma unroll
        for (int kk = 0; kk < 4; ++kk)
            acc = __builtin_amdgcn_mfma_f32_16x16x32_bf16(ax[kk], w[kk * 4 + quad], acc, 0, 0, 0);
#pragma unroll
        for (int r = 0; r < 4; ++r)
            hrow[(quad * 4 + r) * 136 + n0 * 16 + m_] = f2bf(fmaxf(acc[r], 0.f));
    }

    // A-fragments of h from LDS
    short8 ah[4];
#pragma unroll
    for (int kk = 0; kk < 4; ++kk)
        ah[kk] = *(const short8*)&hrow[m_ * 136 + kk * 32 + quad * 8];

    // ---- enc2: emb = h @ W2 + b2; C -> LDS (stride 72) ----
#pragma unroll
    for (int n0 = 0; n0 < 4; ++n0) {
        float bv = b2[n0 * 16 + m_];
        f32x4 acc = {bv, bv, bv, bv};
        const short8* w = (const short8*)(W2t + (size_t)(n0 * 16 + m_) * 128);
#pragma unroll
        for (int kk = 0; kk < 4; ++kk)
            acc = __builtin_amdgcn_mfma_f32_16x16x32_bf16(ah[kk], w[kk * 4 + quad], acc, 0, 0, 0);
#pragma unroll
        for (int r = 0; r < 4; ++r)
            hrow[(quad * 4 + r) * 72 + n0 * 16 + m_] = f2bf(acc[r]);
    }

    // A-fragments of emb from LDS (K=64 -> 2 frags)
    short8 ae[2];
#pragma unroll
    for (int kk = 0; kk < 2; ++kk)
        ae[kk] = *(const short8*)&hrow[m_ * 72 + kk * 32 + quad * 8];

    // coalesced emb_b store (2 x 1KB insts per wave)
    {
        short8 r0 = *(const short8*)&hrow[srow * 72 + scol];
        short8 r1 = *(const short8*)&hrow[(srow + 8) * 72 + scol];
        *(short8*)(emb_b + (size_t)(rbase + srow) * 64 + scol) = r0;
        *(short8*)(emb_b + (size_t)(rbase + 8 + srow) * 64 + scol) = r1;
    }

    // ---- Q, K, V: C -> LDS -> coalesced store ----
    const u16*   Wt3[3] = {Qt, Kt, Vt};
    const float* Bb3[3] = {qbv, kbv, vbv};
    u16*         Ob3[3] = {Qb, Kb, Vb};
#pragma unroll
    for (int m3 = 0; m3 < 3; ++m3) {
        const u16* Wt = Wt3[m3];
        const float* bp = Bb3[m3];
        u16* O = Ob3[m3];
#pragma unroll
        for (int n0 = 0; n0 < 4; ++n0) {
            float bv = bp[n0 * 16 + m_];
            f32x4 acc = {bv, bv, bv, bv};
            const short8* w = (const short8*)(Wt + (size_t)(n0 * 16 + m_) * 64);
#pragma unroll
            for (int kk = 0; kk < 2; ++kk)
                acc = __builtin_amdgcn_mfma_f32_16x16x32_bf16(ae[kk], w[kk * 4 + quad], acc, 0, 0, 0);
#pragma unroll
            for (int r = 0; r < 4; ++r)
                hrow[(quad * 4 + r) * 72 + n0 * 16 + m_] = f2bf(acc[r]);
        }
        short8 r0 = *(const short8*)&hrow[srow * 72 + scol];
        short8 r1 = *(const short8*)&hrow[(srow + 8) * 72 + scol];
        *(short8*)(O + (size_t)(rbase + srow) * 64 + scol) = r0;
        *(short8*)(O + (size_t)(rbase + 8 + srow) * 64 + scol) = r1;
    }
}

// ---------------- fused chem attention: scores + exp + Z + scatter, one edge pass ----------------
// No max-subtraction: scores sigma ~0.3 (1/sqrt(fan_in) init), exp(s) safe in fp32.
__global__ __launch_bounds__(256) void chem_attn(const u16* __restrict__ Qb,
                                                 const u16* __restrict__ Kb,
                                                 const int* __restrict__ chem,
                                                 int* __restrict__ cnt,
                                                 uint2* __restrict__ swlist,
                                                 float* __restrict__ Zp)
{
    __shared__ float wsum[4];
    int tid = threadIdx.x;
    int lane = tid & 63, wave = tid >> 6;
    int sub = lane & 7;             // 16B chunk within the 128B row
    int eo  = lane >> 3;            // which of 8 edges per wave
    int gw  = blockIdx.x * 4 + wave;
    float zsum = 0.f;
    for (int base = gw * 8; base < ECHEM; base += SC_GRID * 4 * 8) {
        int e  = base + eo;
        int ec = e < ECHEM ? e : (ECHEM - 1);
        int src = chem[ec];
        int dst = chem[ECHEM + ec];
        uint4 qv = ((const uint4*)(Qb + (size_t)dst * 64))[sub];
        uint4 kv = ((const uint4*)(Kb + (size_t)src * 64))[sub];
        float p = bprod(qv.x, kv.x) + bprod(qv.y, kv.y) + bprod(qv.z, kv.z) + bprod(qv.w, kv.w);
        p += __shfl_xor(p, 1);
        p += __shfl_xor(p, 2);
        p += __shfl_xor(p, 4);
        float w = __expf(p * 0.125f);
        if (sub == 0 && e < ECHEM) {
            zsum += w;
            int pos = atomicAdd(&cnt[dst], 1);
            if (pos < CHEM_CAP)
                swlist[dst * CHEM_CAP + pos] = make_uint2((unsigned)src, __float_as_uint(w));
        }
    }
    for (int off = 1; off < 64; off <<= 1) zsum += __shfl_xor(zsum, off);
    if (lane == 0) wsum[wave] = zsum;
    __syncthreads();
    if (tid == 0) atomicAdd(Zp, wsum[0] + wsum[1] + wsum[2] + wsum[3]);
}

// ---------------- fused chem aggregation + msg GEMM: Mp = relu((emb + attnV) @ msg_w + b) ----------------
// Wave computes its own 16 dst rows into LDS, then MFMAs them; Mp staged via LDS for coalesced stores.
__global__ __launch_bounds__(256) void chem_agg_msg(const u16* __restrict__ emb_b,
                                                    const u16* __restrict__ Vb,
                                                    const int* __restrict__ cnt,
                                                    const uint2* __restrict__ swlist,
                                                    const float* __restrict__ Zp,
                                                    const u16* __restrict__ Msgt,
                                                    const float* __restrict__ mb,
                                                    u16* __restrict__ Mpb)
{
    __shared__ u16 eb[4][16 * 72];
    const int tid = threadIdx.x, wave = tid >> 6, lane = tid & 63;
    const int m_ = lane & 15, quad = lane >> 4;
    const int d0 = blockIdx.x * 64 + wave * 16;
    const int srow = lane >> 3, scol = (lane & 7) * 8;
    const float invZ = 1.f / Zp[0];
    u16* erow = &eb[wave][0];
#pragma unroll 1
    for (int t = 0; t < 16; ++t) {
        int d = d0 + t;
        int c = cnt[d]; if (c > CHEM_CAP) c = CHEM_CAP;
        int sv = 0; float wv = 0.f;
        if (lane < c) {
            uint2 p = swlist[d * CHEM_CAP + lane];
            sv = (int)p.x; wv = __uint_as_float(p.y);
        }
        float acc = 0.f;
        for (int i = 0; i < c; ++i) {
            int s = __shfl(sv, i);
            float w = __shfl(wv, i);
            acc += w * bf2f(Vb[(size_t)s * 64 + lane]);
        }
        float v = bf2f(emb_b[(size_t)d * 64 + lane]) + acc * invZ;
        erow[t * 72 + lane] = f2bf(v);
    }
    // msg GEMM on this wave's 16 rows
    short8 a0 = *(const short8*)&erow[m_ * 72 + quad * 8];
    short8 a1 = *(const short8*)&erow[m_ * 72 + 32 + quad * 8];
#pragma unroll
    for (int n0 = 0; n0 < 4; ++n0) {
        float bv = mb[n0 * 16 + m_];
        f32x4 acc = {bv, bv, bv, bv};
        const short8* w = (const short8*)(Msgt + (size_t)(n0 * 16 + m_) * 64);
        acc = __builtin_amdgcn_mfma_f32_16x16x32_bf16(a0, w[quad], acc, 0, 0, 0);
        acc = __builtin_amdgcn_mfma_f32_16x16x32_bf16(a1, w[4 + quad], acc, 0, 0, 0);
#pragma unroll
        for (int r = 0; r < 4; ++r)
            erow[(quad * 4 + r) * 72 + n0 * 16 + m_] = f2bf(fmaxf(acc[r], 0.f));
    }
    short8 r0 = *(const short8*)&erow[srow * 72 + scol];
    short8 r1 = *(const short8*)&erow[(srow + 8) * 72 + scol];
    *(short8*)(Mpb + (size_t)(d0 + srow) * 64 + scol) = r0;
    *(short8*)(Mpb + (size_t)(d0 + 8 + srow) * 64 + scol) = r1;
}

// ---------------- p2p bucket: two-phase LDS histogram ----------------
__global__ __launch_bounds__(256) void p2p_bucket(const int* __restrict__ p2p,
                                                  int* __restrict__ cnt,
                                                  int* __restrict__ list)
{
    __shared__ int lhist[NPOS];
    __shared__ int lbase[NPOS];
    int tid = threadIdx.x;
    for (int i = tid; i < NPOS; i += 256) lhist[i] = 0;
    __syncthreads();
    const int chunk = (EP2P + PB_BLOCKS - 1) / PB_BLOCKS;   // 6250
    int e0 = blockIdx.x * chunk;
    int e1 = e0 + chunk; if (e1 > EP2P) e1 = EP2P;
    for (int e = e0 + tid; e < e1; e += 256)
        atomicAdd(&lhist[p2p[EP2P + e]], 1);
    __syncthreads();
    for (int i = tid; i < NPOS; i += 256) {
        lbase[i] = atomicAdd(&cnt[i], lhist[i]);   // one global atomic per (block,dst)
        lhist[i] = 0;
    }
    __syncthreads();
    for (int e = e0 + tid; e < e1; e += 256) {
        int d = p2p[EP2P + e];
        int p = lbase[d] + atomicAdd(&lhist[d], 1);
        if (p < P2P_CAP) list[d * P2P_CAP + p] = p2p[e];
    }
}

// ---------------- p2p segment-sum of Mp (bf16), 8-way split per dst, atomic partials ----------------
__global__ __launch_bounds__(256) void p2p_agg(const u16* __restrict__ Mpb,
                                               const int* __restrict__ cnt,
                                               const int* __restrict__ list,
                                               float* __restrict__ pos_agg)
{
    __shared__ float part[4 * 64];
    int d = blockIdx.x >> 3;                 // / AGG_SPLIT
    int sp = blockIdx.x & (AGG_SPLIT - 1);
    int wave = threadIdx.x >> 6, lane = threadIdx.x & 63;
    int c = cnt[d];
    int cl = c > P2P_CAP ? P2P_CAP : c;
    int seg = (cl + AGG_SPLIT - 1) / AGG_SPLIT;
    int i0b = sp * seg;
    int i1 = i0b + seg; if (i1 > cl) i1 = cl;
    float acc = 0.f;
    for (int i0 = i0b + wave * 64; i0 < i1; i0 += 256) {
        int n = i1 - i0; if (n > 64) n = 64;
        int sv = (lane < n) ? list[d * P2P_CAP + i0 + lane] : 0;
        for (int i = 0; i < n; ++i) {
            int s = __shfl(sv, i);
            acc += bf2f(Mpb[(size_t)s * 64 + lane]);
        }
    }
    part[wave * 64 + lane] = acc;
    __syncthreads();
    if (wave == 0) {
        float t = part[lane] + part[64 + lane] + part[128 + lane] + part[192 + lane];
        atomicAdd(&pos_agg[d * 64 + lane], t);
    }
}

// ---------------- position update: pos_out = relu([pos_in, agg/cnt] @ W + b) ----------------
__global__ __launch_bounds__(256) void pos_update(const float* __restrict__ pos_in,
                                                  const float* __restrict__ agg,   // raw sums
                                                  const int* __restrict__ cnt,
                                                  const float* __restrict__ W,
                                                  const float* __restrict__ bias,
                                                  float* __restrict__ pos_out)
{
    int idx = blockIdx.x * 256 + threadIdx.x;
    if (idx >= NPOS * EMB) return;
    int r = idx >> 6, j = idx & 63;
    int c = cnt[r];
    float invc = 1.f / (float)(c < 1 ? 1 : c);
    float am = bias[j], aa = 0.f;
    const float* pr = pos_in + r * 64;
    const float* ar = agg + r * 64;
#pragma unroll 8
    for (int k = 0; k < 64; ++k) am += pr[k] * W[k * 64 + j];
#pragma unroll 8
    for (int k = 0; k < 64; ++k) aa += ar[k] * W[(64 + k) * 64 + j];
    pos_out[idx] = fmaxf(am + aa * invc, 0.f);
}

// ---------------- small fp32 linear (p2t messages, 320 rows) ----------------
template<int K, int M, bool RELU>
__global__ __launch_bounds__(256) void linear_rows(const float* __restrict__ A,
                                                   const float* __restrict__ W,
                                                   const float* __restrict__ bias,
                                                   float* __restrict__ out, int N)
{
    int r = blockIdx.x * 256 + threadIdx.x;
    if (r >= N) return;
    const float4* a4 = (const float4*)(A + (size_t)r * K);
    float* o = out + (size_t)r * M;
#pragma unroll 1
    for (int j0 = 0; j0 < M; j0 += 32) {
        float acc[32];
#pragma unroll
        for (int j = 0; j < 32; ++j) acc[j] = bias[j0 + j];
#pragma unroll 2
        for (int k4 = 0; k4 < K / 4; ++k4) {
            float4 av = a4[k4];
            const float* w0 = W + (size_t)(4 * k4) * M + j0;
#pragma unroll
            for (int j = 0; j < 32; ++j) acc[j] += av.x * w0[j];
            const float* w1 = w0 + M;
#pragma unroll
            for (int j = 0; j < 32; ++j) acc[j] += av.y * w1[j];
            const float* w2 = w1 + M;
#pragma unroll
            for (int j = 0; j < 32; ++j) acc[j] += av.z * w2[j];
            const float* w3 = w2 + M;
#pragma unroll
            for (int j = 0; j < 32; ++j) acc[j] += av.w * w3[j];
        }
#pragma unroll
        for (int j = 0; j < 32; ++j) {
            float v = acc[j];
            if (RELU) v = fmaxf(v, 0.f);
            o[j0 + j] = v;
        }
    }
}

// ---------------- p2t team rounds + game head (single block) ----------------
__global__ __launch_bounds__(256) void p2t_head(
    const float* __restrict__ Mt,
    const int* __restrict__ p2t_edges,
    const float* __restrict__ upd_w, const float* __restrict__ upd_b,
    const int* __restrict__ team_indices,
    const float* __restrict__ team_table,
    const int* __restrict__ home_p, const int* __restrict__ away_p,
    const float* __restrict__ gp_w1, const float* __restrict__ gp_b1,
    const float* __restrict__ gp_w2, const float* __restrict__ gp_b2,
    const float* __restrict__ gp_w3, const float* __restrict__ gp_b3,
    float* __restrict__ out)
{
    __shared__ int   tcnt[NT];
    __shared__ int   tlist[NT * T2_CAP];
    __shared__ float aggbar[NT * 64];
    __shared__ float teamA[NT * 64];
    __shared__ float teamB[NT * 64];
    __shared__ float z1[128];
    __shared__ float z2[64];
    int tid = threadIdx.x;

    if (tid < NT) tcnt[tid] = 0;
    __syncthreads();
    for (int e = tid; e < EP2T; e += 256) {
        int s = p2t_edges[e], d = p2t_edges[EP2T + e];
        int p = atomicAdd(&tcnt[d], 1);
        if (p < T2_CAP) tlist[d * T2_CAP + p] = s;
    }
    __syncthreads();
    for (int i = tid; i < NT * 64; i += 256) {
        int d = i >> 6, c = i & 63;
        int cn = tcnt[d];
        int cl = cn > T2_CAP ? T2_CAP : cn;
        float acc = 0.f;
        for (int j = 0; j < cl; ++j) acc += Mt[tlist[d * T2_CAP + j] * 64 + c];
        float dv = cn < 1 ? 1.f : (float)cn;
        aggbar[i] = acc / dv;
        teamA[i] = team_table[team_indices[d] * 64 + c];
    }
    __syncthreads();

    float* tin = teamA; float* tout = teamB;
    for (int round = 0; round < 3; ++round) {
        for (int i = tid; i < NT * 64; i += 256) {
            int r = i >> 6, j = i & 63;
            float acc = upd_b[j];
            for (int k = 0; k < 64; ++k) acc += tin[r * 64 + k] * upd_w[k * 64 + j];
            for (int k = 0; k < 64; ++k) acc += aggbar[r * 64 + k] * upd_w[(64 + k) * 64 + j];
            tout[i] = fmaxf(acc, 0.f);
        }
        __syncthreads();
        float* tmp = tin; tin = tout; tout = tmp;
    }

    int home = home_p[0], away = away_p[0];
    if (tid < 128) {
        float acc = gp_b1[tid];
        for (int k = 0; k < 128; ++k) {
            float g = (k < 64) ? tin[home * 64 + k] : tin[away * 64 + (k - 64)];
            acc += g * gp_w1[k * 128 + tid];
        }
        z1[tid] = fmaxf(acc, 0.f);
    }
    __syncthreads();
    if (tid < 64) {
        float acc = gp_b2[tid];
        for (int k = 0; k < 128; ++k) acc += z1[k] * gp_w2[k * 64 + tid];
        z2[tid] = fmaxf(acc, 0.f);
    }
    __syncthreads();
    if (tid == 0) {
        float acc = gp_b3[0];
        for (int k = 0; k < 64; ++k) acc += z2[k] * gp_w3[k];
        out[0] = 1.f / (1.f + __expf(-acc));
    }
}

// ---------------- host launcher ----------------
extern "C" void kernel_launch(void* const* d_in, const int* in_sizes, int n_in,
                              void* d_out, int out_size, void* d_ws, size_t ws_size,
                              hipStream_t stream)
{
    const float* X        = (const float*)d_in[0];
    const int*   pos_idx  = (const int*)d_in[1];
    const int*   team_idx = (const int*)d_in[2];
    const int*   p2p      = (const int*)d_in[3];
    const int*   p2t      = (const int*)d_in[4];
    const int*   chem     = (const int*)d_in[5];
    const int*   home_p   = (const int*)d_in[6];
    const int*   away_p   = (const int*)d_in[7];
    const float* enc_w1   = (const float*)d_in[8];
    const float* enc_b1   = (const float*)d_in[9];
    const float* enc_w2   = (const float*)d_in[10];
    const float* enc_b2   = (const float*)d_in[11];
    const float* pos_tab  = (const float*)d_in[12];
    const float* team_tab = (const float*)d_in[13];
    const float* q_w = (const float*)d_in[14]; const float* q_b = (const float*)d_in[15];
    const float* k_w = (const float*)d_in[16]; const float* k_b = (const float*)d_in[17];
    const float* v_w = (const float*)d_in[18]; const float* v_b = (const float*)d_in[19];
    const float* p2p_msg_w = (const float*)d_in[20]; const float* p2p_msg_b = (const float*)d_in[21];
    const float* p2p_upd_w = (const float*)d_in[22]; const float* p2p_upd_b = (const float*)d_in[23];
    const float* p2t_msg_w = (const float*)d_in[24]; const float* p2t_msg_b = (const float*)d_in[25];
    const float* p2t_upd_w = (const float*)d_in[26]; const float* p2t_upd_b = (const float*)d_in[27];
    const float* gp_w1 = (const float*)d_in[28]; const float* gp_b1 = (const float*)d_in[29];
    const float* gp_w2 = (const float*)d_in[30]; const float* gp_b2 = (const float*)d_in[31];
    const float* gp_w3 = (const float*)d_in[32]; const float* gp_b3 = (const float*)d_in[33];
    float* out = (float*)d_out;

    // ---- workspace layout (bytes), peak ~183 MB ----
    char* ws = (char*)d_ws;
    uint2*    swlist    = (uint2*)(ws + 0);            // NP*CHEM_CAP*8 = 51.2MB
    u16*      emb_b     = (u16*)  (ws + 51200000);     // NP*64 bf16 = 25.6MB
    u16*      Qb        = (u16*)  (ws + 76800000);
    u16*      Kb        = (u16*)  (ws + 102400000);
    u16*      Vb        = (u16*)  (ws + 128000000);
    u16*      Mpb       = (u16*)  (ws + 153600000);
    int*      p2p_list  = (int*)  (ws + 179200000);    // 2.62MB
    int*      chem_cnt  = (int*)  (ws + 181821440);    // 800KB
    int*      p2p_cnt   = (int*)  (ws + 182621440);
    float*    pos_agg   = (float*)(ws + 182622720);
    float*    posA      = (float*)(ws + 182704640);
    float*    posB      = (float*)(ws + 182786560);
    float*    Mt        = (float*)(ws + 182868480);
    float*    Zp        = (float*)(ws + 182950400);
    u16*      Wpack     = (u16*)  (ws + 182950416);    // 80KB transposed bf16 weights
    u16* W1t  = Wpack;
    u16* W2t  = Wpack + 16384;
    u16* Qt   = Wpack + 24576;
    u16* Kt   = Wpack + 28672;
    u16* Vt   = Wpack + 32768;
    u16* Msgt = Wpack + 36864;

    const int NB_NP = (NP + 255) / 256;

    hipLaunchKernelGGL(init_kernel, dim3(NB_NP), dim3(256), 0, stream,
                       chem_cnt, p2p_cnt, Zp, pos_idx, pos_tab, posA, pos_agg,
                       enc_w1, enc_w2, q_w, k_w, v_w, p2p_msg_w, Wpack);
    // fused encoder + QKV (MFMA, coalesced stores)
    hipLaunchKernelGGL(mfma_enc, dim3(NP / 64), dim3(256), 0, stream,
                       X, W1t, W2t, Qt, Kt, Vt,
                       enc_b1, enc_b2, q_b, k_b, v_b,
                       emb_b, Qb, Kb, Vb);
    // fused chem attention: scores + exp + Z + scatter
    hipLaunchKernelGGL(chem_attn, dim3(SC_GRID), dim3(256), 0, stream,
                       Qb, Kb, chem, chem_cnt, swlist, Zp);
    // fused chem aggregation + p2p message GEMM
    hipLaunchKernelGGL(chem_agg_msg, dim3(NP / 64), dim3(256), 0, stream,
                       emb_b, Vb, chem_cnt, swlist, Zp, Msgt, p2p_msg_b, Mpb);
    // p2p phase
    hipLaunchKernelGGL(p2p_bucket, dim3(PB_BLOCKS), dim3(256), 0, stream, p2p, p2p_cnt, p2p_list);
    hipLaunchKernelGGL(p2p_agg, dim3(NPOS * AGG_SPLIT), dim3(256), 0, stream,
                       Mpb, p2p_cnt, p2p_list, pos_agg);
    hipLaunchKernelGGL(pos_update, dim3((NPOS * EMB + 255) / 256), dim3(256), 0, stream,
                       posA, pos_agg, p2p_cnt, p2p_upd_w, p2p_upd_b, posB);
    hipLaunchKernelGGL(pos_update, dim3((NPOS * EMB + 255) / 256), dim3(256), 0, stream,
                       posB, pos_agg, p2p_cnt, p2p_upd_w, p2p_upd_b, posA);
    hipLaunchKernelGGL(pos_update, dim3((NPOS * EMB + 255) / 256), dim3(256), 0, stream,
                       posA, pos_agg, p2p_cnt, p2p_upd_w, p2p_upd_b, posB);
    // p2t phase + head
    hipLaunchKernelGGL((linear_rows<64,64,true>), dim3((NPOS + 255) / 256), dim3(256), 0, stream,
                       posB, p2t_msg_w, p2t_msg_b, Mt, NPOS);
    hipLaunchKernelGGL(p2t_head, dim3(1), dim3(256), 0, stream,
                       Mt, p2t, p2t_upd_w, p2t_upd_b, team_idx, team_tab, home_p, away_p,
                       gp_w1, gp_b1, gp_w2, gp_b2, gp_w3, gp_b3, out);
}

// Round 7
// 619.646 us; speedup vs baseline: 1.2136x; 1.2136x over previous
//
#include <hip/hip_runtime.h>
#include <hip/hip_bf16.h>

// ---------------- problem constants ----------------
#define NP     200000
#define NPOS   320
#define NT     32
#define FEAT   128
#define EMB    64
#define HID    128
#define EP2P   400000
#define EP2T   640
#define ECHEM  1000000

#define CHEM_CAP 32
#define P2P_CAP  2048
#define T2_CAP   64
#define SC_GRID  2048
#define PB_BLOCKS 64
#define AGG_SPLIT 8

typedef unsigned short u16;
typedef __attribute__((ext_vector_type(8))) short short8;   // 8 bf16 = 4 VGPRs
typedef __attribute__((ext_vector_type(4))) float f32x4;

static __device__ inline u16 f2bf(float f) {               // RNE fp32->bf16
    unsigned u = __float_as_uint(f);
    return (u16)((u + 0x7fffu + ((u >> 16) & 1u)) >> 16);
}
static __device__ inline float bf2f(u16 h) {
    return __uint_as_float(((unsigned)h) << 16);
}
static __device__ inline float bprod(unsigned a, unsigned b) {  // dot of 2 packed bf16 pairs
    float a0 = __uint_as_float(a << 16), a1 = __uint_as_float(a & 0xffff0000u);
    float b0 = __uint_as_float(b << 16), b1 = __uint_as_float(b & 0xffff0000u);
    return fmaf(a0, b0, a1 * b1);
}

// ---------------- init: counters, pos embeds, pos_agg zero, weight transpose->bf16 ----------------
__global__ __launch_bounds__(256) void init_kernel(int* __restrict__ chem_cnt,
                                                   int* __restrict__ p2p_cnt,
                                                   float* __restrict__ Zp,
                                                   const int* __restrict__ pos_idx,
                                                   const float* __restrict__ pos_table,
                                                   float* __restrict__ pos0,
                                                   float* __restrict__ pos_agg,
                                                   const float* __restrict__ w1,
                                                   const float* __restrict__ w2,
                                                   const float* __restrict__ qw,
                                                   const float* __restrict__ kw,
                                                   const float* __restrict__ vw,
                                                   const float* __restrict__ mw,
                                                   u16* __restrict__ Wpack)
{
    int t = blockIdx.x * 256 + threadIdx.x;
    if (t < NP) chem_cnt[t] = 0;
    if (t < NPOS) p2p_cnt[t] = 0;
    if (t < NPOS * EMB) {
        pos0[t] = pos_table[pos_idx[t >> 6] * EMB + (t & 63)];
        pos_agg[t] = 0.f;
    }
    if (t == 0) *Zp = 0.f;
    if (t < 40960) {
        float v;
        if (t < 16384)        { int i = t;         v = w1[(i & 127) * 128 + (i >> 7)]; }
        else if (t < 24576)   { int i = t - 16384; v = w2[(i & 127) * 64  + (i >> 7)]; }
        else if (t < 28672)   { int i = t - 24576; v = qw[(i & 63) * 64 + (i >> 6)]; }
        else if (t < 32768)   { int i = t - 28672; v = kw[(i & 63) * 64 + (i >> 6)]; }
        else if (t < 36864)   { int i = t - 32768; v = vw[(i & 63) * 64 + (i >> 6)]; }
        else                  { int i = t - 36864; v = mw[(i & 63) * 64 + (i >> 6)]; }
        Wpack[t] = f2bf(v);
    }
}

// ---------------- fused MFMA encoder: X(fp32) -> h -> emb(fp32) -> Q,K,V  (R4-fastest variant) ----------------
__global__ __launch_bounds__(256) void mfma_enc(
    const float* __restrict__ X,
    const u16* __restrict__ W1t, const u16* __restrict__ W2t,
    const u16* __restrict__ Qt,  const u16* __restrict__ Kt, const u16* __restrict__ Vt,
    const float* __restrict__ b1, const float* __restrict__ b2,
    const float* __restrict__ qbv, const float* __restrict__ kbv, const float* __restrict__ vbv,
    float* __restrict__ emb,
    u16* __restrict__ Qb, u16* __restrict__ Kb, u16* __restrict__ Vb)
{
    __shared__ u16 hb[4][16 * 136];   // per-wave h tile, row stride 136 (pad 8)
    __shared__ u16 eb[4][16 * 72];    // per-wave emb tile, row stride 72
    const int tid = threadIdx.x, wave = tid >> 6, lane = tid & 63;
    const int m_ = lane & 15, quad = lane >> 4;
    const int rbase = blockIdx.x * 64 + wave * 16;

    // A-fragments of X: load fp32, round to bf16 in-register
    const float4* xrow = (const float4*)(X + (size_t)(rbase + m_) * 128);
    short8 ax[4];
#pragma unroll
    for (int kk = 0; kk < 4; ++kk) {
        float4 u = xrow[kk * 8 + quad * 2];
        float4 v = xrow[kk * 8 + quad * 2 + 1];
        short8 t;
        t[0] = (short)f2bf(u.x); t[1] = (short)f2bf(u.y);
        t[2] = (short)f2bf(u.z); t[3] = (short)f2bf(u.w);
        t[4] = (short)f2bf(v.x); t[5] = (short)f2bf(v.y);
        t[6] = (short)f2bf(v.z); t[7] = (short)f2bf(v.w);
        ax[kk] = t;
    }

    u16* hrow = &hb[wave][0];
    // ---- enc1: h = relu(X @ W1 + b1), 8 col-tiles of 16 ----
#pragma unroll
    for (int n0 = 0; n0 < 8; ++n0) {
        float bv = b1[n0 * 16 + m_];
        f32x4 acc = {bv, bv, bv, bv};
        const short8* w = (const short8*)(W1t + (size_t)(n0 * 16 + m_) * 128);
#pragma unroll
        for (int kk = 0; kk < 4; ++kk)
            acc = __builtin_amdgcn_mfma_f32_16x16x32_bf16(ax[kk], w[kk * 4 + quad], acc, 0, 0, 0);
#pragma unroll
        for (int r = 0; r < 4; ++r)
            hrow[(quad * 4 + r) * 136 + n0 * 16 + m_] = f2bf(fmaxf(acc[r], 0.f));
    }

    // A-fragments of h from LDS
    short8 ah[4];
#pragma unroll
    for (int kk = 0; kk < 4; ++kk)
        ah[kk] = *(const short8*)&hrow[m_ * 136 + kk * 32 + quad * 8];

    u16* erow = &eb[wave][0];
    // ---- enc2: emb = h @ W2 + b2, 4 col-tiles ----
#pragma unroll
    for (int n0 = 0; n0 < 4; ++n0) {
        float bv = b2[n0 * 16 + m_];
        f32x4 acc = {bv, bv, bv, bv};
        const short8* w = (const short8*)(W2t + (size_t)(n0 * 16 + m_) * 128);
#pragma unroll
        for (int kk = 0; kk < 4; ++kk)
            acc = __builtin_amdgcn_mfma_f32_16x16x32_bf16(ah[kk], w[kk * 4 + quad], acc, 0, 0, 0);
#pragma unroll
        for (int r = 0; r < 4; ++r) {
            float v = acc[r];
            emb[(size_t)(rbase + quad * 4 + r) * 64 + n0 * 16 + m_] = v;
            erow[(quad * 4 + r) * 72 + n0 * 16 + m_] = f2bf(v);
        }
    }

    // A-fragments of emb from LDS (K=64 -> 2 frags)
    short8 ae[2];
#pragma unroll
    for (int kk = 0; kk < 2; ++kk)
        ae[kk] = *(const short8*)&erow[m_ * 72 + kk * 32 + quad * 8];

    // ---- Q, K, V ----
    const u16*   Wt3[3] = {Qt, Kt, Vt};
    const float* Bb3[3] = {qbv, kbv, vbv};
    u16*         Ob3[3] = {Qb, Kb, Vb};
#pragma unroll
    for (int m3 = 0; m3 < 3; ++m3) {
        const u16* Wt = Wt3[m3];
        const float* bp = Bb3[m3];
        u16* O = Ob3[m3];
#pragma unroll
        for (int n0 = 0; n0 < 4; ++n0) {
            float bv = bp[n0 * 16 + m_];
            f32x4 acc = {bv, bv, bv, bv};
            const short8* w = (const short8*)(Wt + (size_t)(n0 * 16 + m_) * 64);
#pragma unroll
            for (int kk = 0; kk < 2; ++kk)
                acc = __builtin_amdgcn_mfma_f32_16x16x32_bf16(ae[kk], w[kk * 4 + quad], acc, 0, 0, 0);
#pragma unroll
            for (int r = 0; r < 4; ++r)
                O[(size_t)(rbase + quad * 4 + r) * 64 + n0 * 16 + m_] = f2bf(acc[r]);
        }
    }
}

// ---------------- fused chem attention: EDGE PER LANE (8x MLP) ----------------
// Per lane: 16 independent 16B loads in flight (full Q row + K row), in-lane dot.
// No max-subtraction: scores sigma ~0.3, exp(s) safe in fp32.
__global__ __launch_bounds__(256) void chem_attn(const u16* __restrict__ Qb,
                                                 const u16* __restrict__ Kb,
                                                 const int* __restrict__ chem,
                                                 int* __restrict__ cnt,
                                                 uint2* __restrict__ swlist,
                                                 float* __restrict__ Zp)
{
    __shared__ float wsum[4];
    int tid = threadIdx.x;
    int lane = tid & 63, wave = tid >> 6;
    float zsum = 0.f;
    for (int e = blockIdx.x * 256 + tid; e < ECHEM; e += SC_GRID * 256) {
        int src = chem[e];
        int dst = chem[ECHEM + e];
        const uint4* q = (const uint4*)(Qb + (size_t)dst * 64);
        const uint4* k = (const uint4*)(Kb + (size_t)src * 64);
        uint4 qv[8], kv[8];
#pragma unroll
        for (int i = 0; i < 8; ++i) qv[i] = q[i];
#pragma unroll
        for (int i = 0; i < 8; ++i) kv[i] = k[i];
        float p = 0.f;
#pragma unroll
        for (int i = 0; i < 8; ++i)
            p += bprod(qv[i].x, kv[i].x) + bprod(qv[i].y, kv[i].y)
               + bprod(qv[i].z, kv[i].z) + bprod(qv[i].w, kv[i].w);
        float w = __expf(p * 0.125f);
        zsum += w;
        int pos = atomicAdd(&cnt[dst], 1);
        if (pos < CHEM_CAP)
            swlist[dst * CHEM_CAP + pos] = make_uint2((unsigned)src, __float_as_uint(w));
    }
    for (int off = 1; off < 64; off <<= 1) zsum += __shfl_xor(zsum, off);
    if (lane == 0) wsum[wave] = zsum;
    __syncthreads();
    if (tid == 0) atomicAdd(Zp, wsum[0] + wsum[1] + wsum[2] + wsum[3]);
}

// ---------------- fused chem aggregation + msg GEMM (4-way unrolled V gather) ----------------
__global__ __launch_bounds__(256) void chem_agg_msg(const float* __restrict__ emb,
                                                    const u16* __restrict__ Vb,
                                                    const int* __restrict__ cnt,
                                                    const uint2* __restrict__ swlist,
                                                    const float* __restrict__ Zp,
                                                    const u16* __restrict__ Msgt,
                                                    const float* __restrict__ mb,
                                                    u16* __restrict__ Mpb)
{
    __shared__ u16 eb[4][16 * 72];
    const int tid = threadIdx.x, wave = tid >> 6, lane = tid & 63;
    const int m_ = lane & 15, quad = lane >> 4;
    const int d0 = blockIdx.x * 64 + wave * 16;
    const int srow = lane >> 3, scol = (lane & 7) * 8;
    const float invZ = 1.f / Zp[0];
    u16* erow = &eb[wave][0];
#pragma unroll 1
    for (int t = 0; t < 16; ++t) {
        int d = d0 + t;
        float base = emb[(size_t)d * 64 + lane];     // independent load, issues early
        int c = cnt[d]; if (c > CHEM_CAP) c = CHEM_CAP;
        int sv = 0; float wv = 0.f;
        if (lane < c) {
            uint2 p = swlist[d * CHEM_CAP + lane];
            sv = (int)p.x; wv = __uint_as_float(p.y);
        }
        float acc = 0.f;
        int i = 0;
        for (; i + 4 <= c; i += 4) {                 // 4 independent gathers in flight
            int s0 = __shfl(sv, i),     s1 = __shfl(sv, i + 1);
            int s2 = __shfl(sv, i + 2), s3 = __shfl(sv, i + 3);
            float w0 = __shfl(wv, i),     w1 = __shfl(wv, i + 1);
            float w2 = __shfl(wv, i + 2), w3 = __shfl(wv, i + 3);
            float v0 = bf2f(Vb[(size_t)s0 * 64 + lane]);
            float v1 = bf2f(Vb[(size_t)s1 * 64 + lane]);
            float v2 = bf2f(Vb[(size_t)s2 * 64 + lane]);
            float v3 = bf2f(Vb[(size_t)s3 * 64 + lane]);
            acc += w0 * v0 + w1 * v1 + w2 * v2 + w3 * v3;
        }
        for (; i < c; ++i) {
            int s = __shfl(sv, i);
            float w = __shfl(wv, i);
            acc += w * bf2f(Vb[(size_t)s * 64 + lane]);
        }
        erow[t * 72 + lane] = f2bf(base + acc * invZ);
    }
    // msg GEMM on this wave's 16 rows
    short8 a0 = *(const short8*)&erow[m_ * 72 + quad * 8];
    short8 a1 = *(const short8*)&erow[m_ * 72 + 32 + quad * 8];
#pragma unroll
    for (int n0 = 0; n0 < 4; ++n0) {
        float bv = mb[n0 * 16 + m_];
        f32x4 acc = {bv, bv, bv, bv};
        const short8* w = (const short8*)(Msgt + (size_t)(n0 * 16 + m_) * 64);
        acc = __builtin_amdgcn_mfma_f32_16x16x32_bf16(a0, w[quad], acc, 0, 0, 0);
        acc = __builtin_amdgcn_mfma_f32_16x16x32_bf16(a1, w[4 + quad], acc, 0, 0, 0);
#pragma unroll
        for (int r = 0; r < 4; ++r)
            erow[(quad * 4 + r) * 72 + n0 * 16 + m_] = f2bf(fmaxf(acc[r], 0.f));
    }
    short8 r0 = *(const short8*)&erow[srow * 72 + scol];
    short8 r1 = *(const short8*)&erow[(srow + 8) * 72 + scol];
    *(short8*)(Mpb + (size_t)(d0 + srow) * 64 + scol) = r0;
    *(short8*)(Mpb + (size_t)(d0 + 8 + srow) * 64 + scol) = r1;
}

// ---------------- p2p bucket: two-phase LDS histogram ----------------
__global__ __launch_bounds__(256) void p2p_bucket(const int* __restrict__ p2p,
                                                  int* __restrict__ cnt,
                                                  int* __restrict__ list)
{
    __shared__ int lhist[NPOS];
    __shared__ int lbase[NPOS];
    int tid = threadIdx.x;
    for (int i = tid; i < NPOS; i += 256) lhist[i] = 0;
    __syncthreads();
    const int chunk = (EP2P + PB_BLOCKS - 1) / PB_BLOCKS;   // 6250
    int e0 = blockIdx.x * chunk;
    int e1 = e0 + chunk; if (e1 > EP2P) e1 = EP2P;
    for (int e = e0 + tid; e < e1; e += 256)
        atomicAdd(&lhist[p2p[EP2P + e]], 1);
    __syncthreads();
    for (int i = tid; i < NPOS; i += 256) {
        lbase[i] = atomicAdd(&cnt[i], lhist[i]);
        lhist[i] = 0;
    }
    __syncthreads();
    for (int e = e0 + tid; e < e1; e += 256) {
        int d = p2p[EP2P + e];
        int p = lbase[d] + atomicAdd(&lhist[d], 1);
        if (p < P2P_CAP) list[d * P2P_CAP + p] = p2p[e];
    }
}

// ---------------- p2p segment-sum of Mp (bf16), split per dst, 4-way unrolled gather ----------------
__global__ __launch_bounds__(256) void p2p_agg(const u16* __restrict__ Mpb,
                                               const int* __restrict__ cnt,
                                               const int* __restrict__ list,
                                               float* __restrict__ pos_agg)
{
    __shared__ float part[4 * 64];
    int d = blockIdx.x >> 3;                 // / AGG_SPLIT
    int sp = blockIdx.x & (AGG_SPLIT - 1);
    int wave = threadIdx.x >> 6, lane = threadIdx.x & 63;
    int c = cnt[d];
    int cl = c > P2P_CAP ? P2P_CAP : c;
    int seg = (cl + AGG_SPLIT - 1) / AGG_SPLIT;
    int i0b = sp * seg;
    int i1 = i0b + seg; if (i1 > cl) i1 = cl;
    float acc = 0.f;
    for (int i0 = i0b + wave * 64; i0 < i1; i0 += 256) {
        int n = i1 - i0; if (n > 64) n = 64;
        int sv = (lane < n) ? list[d * P2P_CAP + i0 + lane] : 0;
        int i = 0;
        for (; i + 4 <= n; i += 4) {
            int s0 = __shfl(sv, i),     s1 = __shfl(sv, i + 1);
            int s2 = __shfl(sv, i + 2), s3 = __shfl(sv, i + 3);
            float v0 = bf2f(Mpb[(size_t)s0 * 64 + lane]);
            float v1 = bf2f(Mpb[(size_t)s1 * 64 + lane]);
            float v2 = bf2f(Mpb[(size_t)s2 * 64 + lane]);
            float v3 = bf2f(Mpb[(size_t)s3 * 64 + lane]);
            acc += v0 + v1 + v2 + v3;
        }
        for (; i < n; ++i) {
            int s = __shfl(sv, i);
            acc += bf2f(Mpb[(size_t)s * 64 + lane]);
        }
    }
    part[wave * 64 + lane] = acc;
    __syncthreads();
    if (wave == 0) {
        float t = part[lane] + part[64 + lane] + part[128 + lane] + part[192 + lane];
        atomicAdd(&pos_agg[d * 64 + lane], t);
    }
}

// ---------------- fused: 3 position-update rounds + p2t message GEMM (row-local) ----------------
// pos rounds are row-parallel: out[r] depends only on in[r] and agg[r]. agg term constant
// across rounds -> precompute aggw once. Block = 4 rows x 64 cols.
__global__ __launch_bounds__(256) void pos_rounds(const float* __restrict__ pos0,
                                                  const float* __restrict__ agg,   // raw sums
                                                  const int* __restrict__ cnt,
                                                  const float* __restrict__ upd_w, // 128x64
                                                  const float* __restrict__ upd_b,
                                                  const float* __restrict__ msg_w, // 64x64
                                                  const float* __restrict__ msg_b,
                                                  float* __restrict__ Mt)          // 320x64
{
    __shared__ float cur[4][64], nxt[4][64], aggw[4][64];
    int tid = threadIdx.x;
    int r = tid >> 6, j = tid & 63;
    int row = blockIdx.x * 4 + r;
    int c = cnt[row];
    float invc = 1.f / (float)(c < 1 ? 1 : c);
    float aw = 0.f;
    const float* ar = agg + row * 64;
#pragma unroll 8
    for (int k = 0; k < 64; ++k) aw += ar[k] * upd_w[(64 + k) * 64 + j];
    aggw[r][j] = aw * invc + upd_b[j];
    cur[r][j] = pos0[row * 64 + j];
    __syncthreads();
#pragma unroll 1
    for (int round = 0; round < 3; ++round) {
        float acc = aggw[r][j];
#pragma unroll 8
        for (int k = 0; k < 64; ++k) acc += cur[r][k] * upd_w[k * 64 + j];
        nxt[r][j] = fmaxf(acc, 0.f);
        __syncthreads();
        cur[r][j] = nxt[r][j];
        __syncthreads();
    }
    float acc = msg_b[j];
#pragma unroll 8
    for (int k = 0; k < 64; ++k) acc += cur[r][k] * msg_w[k * 64 + j];
    Mt[row * 64 + j] = fmaxf(acc, 0.f);
}

// ---------------- p2t team rounds + game head (single block) ----------------
__global__ __launch_bounds__(256) void p2t_head(
    const float* __restrict__ Mt,
    const int* __restrict__ p2t_edges,
    const float* __restrict__ upd_w, const float* __restrict__ upd_b,
    const int* __restrict__ team_indices,
    const float* __restrict__ team_table,
    const int* __restrict__ home_p, const int* __restrict__ away_p,
    const float* __restrict__ gp_w1, const float* __restrict__ gp_b1,
    const float* __restrict__ gp_w2, const float* __restrict__ gp_b2,
    const float* __restrict__ gp_w3, const float* __restrict__ gp_b3,
    float* __restrict__ out)
{
    __shared__ int   tcnt[NT];
    __shared__ int   tlist[NT * T2_CAP];
    __shared__ float aggbar[NT * 64];
    __shared__ float teamA[NT * 64];
    __shared__ float teamB[NT * 64];
    __shared__ float z1[128];
    __shared__ float z2[64];
    int tid = threadIdx.x;

    if (tid < NT) tcnt[tid] = 0;
    __syncthreads();
    for (int e = tid; e < EP2T; e += 256) {
        int s = p2t_edges[e], d = p2t_edges[EP2T + e];
        int p = atomicAdd(&tcnt[d], 1);
        if (p < T2_CAP) tlist[d * T2_CAP + p] = s;
    }
    __syncthreads();
    for (int i = tid; i < NT * 64; i += 256) {
        int d = i >> 6, c = i & 63;
        int cn = tcnt[d];
        int cl = cn > T2_CAP ? T2_CAP : cn;
        float acc = 0.f;
        for (int j = 0; j < cl; ++j) acc += Mt[tlist[d * T2_CAP + j] * 64 + c];
        float dv = cn < 1 ? 1.f : (float)cn;
        aggbar[i] = acc / dv;
        teamA[i] = team_table[team_indices[d] * 64 + c];
    }
    __syncthreads();

    float* tin = teamA; float* tout = teamB;
    for (int round = 0; round < 3; ++round) {
        for (int i = tid; i < NT * 64; i += 256) {
            int r = i >> 6, j = i & 63;
            float acc = upd_b[j];
            for (int k = 0; k < 64; ++k) acc += tin[r * 64 + k] * upd_w[k * 64 + j];
            for (int k = 0; k < 64; ++k) acc += aggbar[r * 64 + k] * upd_w[(64 + k) * 64 + j];
            tout[i] = fmaxf(acc, 0.f);
        }
        __syncthreads();
        float* tmp = tin; tin = tout; tout = tmp;
    }

    int home = home_p[0], away = away_p[0];
    if (tid < 128) {
        float acc = gp_b1[tid];
        for (int k = 0; k < 128; ++k) {
            float g = (k < 64) ? tin[home * 64 + k] : tin[away * 64 + (k - 64)];
            acc += g * gp_w1[k * 128 + tid];
        }
        z1[tid] = fmaxf(acc, 0.f);
    }
    __syncthreads();
    if (tid < 64) {
        float acc = gp_b2[tid];
        for (int k = 0; k < 128; ++k) acc += z1[k] * gp_w2[k * 64 + tid];
        z2[tid] = fmaxf(acc, 0.f);
    }
    __syncthreads();
    if (tid == 0) {
        float acc = gp_b3[0];
        for (int k = 0; k < 64; ++k) acc += z2[k] * gp_w3[k];
        out[0] = 1.f / (1.f + __expf(-acc));
    }
}

// ---------------- host launcher ----------------
extern "C" void kernel_launch(void* const* d_in, const int* in_sizes, int n_in,
                              void* d_out, int out_size, void* d_ws, size_t ws_size,
                              hipStream_t stream)
{
    const float* X        = (const float*)d_in[0];
    const int*   pos_idx  = (const int*)d_in[1];
    const int*   team_idx = (const int*)d_in[2];
    const int*   p2p      = (const int*)d_in[3];
    const int*   p2t      = (const int*)d_in[4];
    const int*   chem     = (const int*)d_in[5];
    const int*   home_p   = (const int*)d_in[6];
    const int*   away_p   = (const int*)d_in[7];
    const float* enc_w1   = (const float*)d_in[8];
    const float* enc_b1   = (const float*)d_in[9];
    const float* enc_w2   = (const float*)d_in[10];
    const float* enc_b2   = (const float*)d_in[11];
    const float* pos_tab  = (const float*)d_in[12];
    const float* team_tab = (const float*)d_in[13];
    const float* q_w = (const float*)d_in[14]; const float* q_b = (const float*)d_in[15];
    const float* k_w = (const float*)d_in[16]; const float* k_b = (const float*)d_in[17];
    const float* v_w = (const float*)d_in[18]; const float* v_b = (const float*)d_in[19];
    const float* p2p_msg_w = (const float*)d_in[20]; const float* p2p_msg_b = (const float*)d_in[21];
    const float* p2p_upd_w = (const float*)d_in[22]; const float* p2p_upd_b = (const float*)d_in[23];
    const float* p2t_msg_w = (const float*)d_in[24]; const float* p2t_msg_b = (const float*)d_in[25];
    const float* p2t_upd_w = (const float*)d_in[26]; const float* p2t_upd_b = (const float*)d_in[27];
    const float* gp_w1 = (const float*)d_in[28]; const float* gp_b1 = (const float*)d_in[29];
    const float* gp_w2 = (const float*)d_in[30]; const float* gp_b2 = (const float*)d_in[31];
    const float* gp_w3 = (const float*)d_in[32]; const float* gp_b3 = (const float*)d_in[33];
    float* out = (float*)d_out;

    // ---- workspace layout (bytes), peak ~210 MB ----
    char* ws = (char*)d_ws;
    uint2*    swlist    = (uint2*)(ws + 0);            // NP*CHEM_CAP*8 = 51.2MB
    float*    emb       = (float*)(ws + 51200000);     // NP*64 fp32 = 51.2MB
    u16*      Qb        = (u16*)  (ws + 102400000);    // NP*64 bf16
    u16*      Kb        = (u16*)  (ws + 128000000);
    u16*      Vb        = (u16*)  (ws + 153600000);
    u16*      Mpb       = (u16*)  (ws + 179200000);
    int*      p2p_list  = (int*)  (ws + 204800000);    // 2.62MB
    int*      chem_cnt  = (int*)  (ws + 207421440);    // 800KB
    int*      p2p_cnt   = (int*)  (ws + 208221440);
    float*    pos_agg   = (float*)(ws + 208222720);
    float*    posA      = (float*)(ws + 208304640);
    float*    Mt        = (float*)(ws + 208386560);
    float*    Zp        = (float*)(ws + 208468480);
    u16*      Wpack     = (u16*)  (ws + 208468496);    // 80KB transposed bf16 weights
    u16* W1t  = Wpack;
    u16* W2t  = Wpack + 16384;
    u16* Qt   = Wpack + 24576;
    u16* Kt   = Wpack + 28672;
    u16* Vt   = Wpack + 32768;
    u16* Msgt = Wpack + 36864;

    const int NB_NP = (NP + 255) / 256;

    hipLaunchKernelGGL(init_kernel, dim3(NB_NP), dim3(256), 0, stream,
                       chem_cnt, p2p_cnt, Zp, pos_idx, pos_tab, posA, pos_agg,
                       enc_w1, enc_w2, q_w, k_w, v_w, p2p_msg_w, Wpack);
    hipLaunchKernelGGL(mfma_enc, dim3(NP / 64), dim3(256), 0, stream,
                       X, W1t, W2t, Qt, Kt, Vt,
                       enc_b1, enc_b2, q_b, k_b, v_b,
                       emb, Qb, Kb, Vb);
    hipLaunchKernelGGL(chem_attn, dim3(SC_GRID), dim3(256), 0, stream,
                       Qb, Kb, chem, chem_cnt, swlist, Zp);
    hipLaunchKernelGGL(chem_agg_msg, dim3(NP / 64), dim3(256), 0, stream,
                       emb, Vb, chem_cnt, swlist, Zp, Msgt, p2p_msg_b, Mpb);
    hipLaunchKernelGGL(p2p_bucket, dim3(PB_BLOCKS), dim3(256), 0, stream, p2p, p2p_cnt, p2p_list);
    hipLaunchKernelGGL(p2p_agg, dim3(NPOS * AGG_SPLIT), dim3(256), 0, stream,
                       Mpb, p2p_cnt, p2p_list, pos_agg);
    hipLaunchKernelGGL(pos_rounds, dim3(NPOS / 4), dim3(256), 0, stream,
                       posA, pos_agg, p2p_cnt, p2p_upd_w, p2p_upd_b,
                       p2t_msg_w, p2t_msg_b, Mt);
    hipLaunchKernelGGL(p2t_head, dim3(1), dim3(256), 0, stream,
                       Mt, p2t, p2t_upd_w, p2t_upd_b, team_idx, team_tab, home_p, away_p,
                       gp_w1, gp_b1, gp_w2, gp_b2, gp_w3, gp_b3, out);
}

// Round 8
// 593.187 us; speedup vs baseline: 1.2678x; 1.0446x over previous
//
#include <hip/hip_runtime.h>
#include <hip/hip_bf16.h>

// ---------------- problem constants ----------------
#define NP     200000
#define NPOS   320
#define NT     32
#define FEAT   128
#define EMB    64
#define HID    128
#define EP2P   400000
#define EP2T   640
#define ECHEM  1000000

#define CHEM_CAP 32
#define P2P_CAP  2048
#define T2_CAP   64
#define SC_GRID  2048
#define PB_BLOCKS 64
#define AGG_SPLIT 8
#define ENC_GRID 1024
#define NCHUNK   (NP / 64)    // 3125

typedef unsigned short u16;
typedef __attribute__((ext_vector_type(8))) short short8;   // 8 bf16 = 4 VGPRs
typedef __attribute__((ext_vector_type(4))) float f32x4;

static __device__ inline u16 f2bf(float f) {               // RNE fp32->bf16
    unsigned u = __float_as_uint(f);
    return (u16)((u + 0x7fffu + ((u >> 16) & 1u)) >> 16);
}
static __device__ inline float bf2f(u16 h) {
    return __uint_as_float(((unsigned)h) << 16);
}

// ---------------- init: counters, pos embeds, pos_agg zero, weight transpose->bf16 ----------------
__global__ __launch_bounds__(256) void init_kernel(int* __restrict__ chem_cnt,
                                                   int* __restrict__ p2p_cnt,
                                                   float* __restrict__ Zp,
                                                   const int* __restrict__ pos_idx,
                                                   const float* __restrict__ pos_table,
                                                   float* __restrict__ pos0,
                                                   float* __restrict__ pos_agg,
                                                   const float* __restrict__ w1,
                                                   const float* __restrict__ w2,
                                                   const float* __restrict__ qw,
                                                   const float* __restrict__ kw,
                                                   const float* __restrict__ vw,
                                                   const float* __restrict__ mw,
                                                   u16* __restrict__ Wpack)
{
    int t = blockIdx.x * 256 + threadIdx.x;
    if (t < NP) chem_cnt[t] = 0;
    if (t < NPOS) p2p_cnt[t] = 0;
    if (t < NPOS * EMB) {
        pos0[t] = pos_table[pos_idx[t >> 6] * EMB + (t & 63)];
        pos_agg[t] = 0.f;
    }
    if (t == 0) *Zp = 0.f;
    if (t < 40960) {
        float v;
        if (t < 16384)        { int i = t;         v = w1[(i & 127) * 128 + (i >> 7)]; }
        else if (t < 24576)   { int i = t - 16384; v = w2[(i & 127) * 64  + (i >> 7)]; }
        else if (t < 28672)   { int i = t - 24576; v = qw[(i & 63) * 64 + (i >> 6)]; }
        else if (t < 32768)   { int i = t - 28672; v = kw[(i & 63) * 64 + (i >> 6)]; }
        else if (t < 36864)   { int i = t - 32768; v = vw[(i & 63) * 64 + (i >> 6)]; }
        else                  { int i = t - 36864; v = mw[(i & 63) * 64 + (i >> 6)]; }
        Wpack[t] = f2bf(v);
    }
}

// ---------------- fused MFMA encoder: persistent grid + raw-X prefetch of next chunk ----------------
// R4-proven body (separate hb/eb, fp32 emb, direct C-layout stores). The next chunk's X
// float4 loads are issued BEFORE processing the current chunk, hiding ~900cyc HBM latency
// under the current chunk's MFMA + stores.
__global__ __launch_bounds__(256) void mfma_enc(
    const float* __restrict__ X,
    const u16* __restrict__ W1t, const u16* __restrict__ W2t,
    const u16* __restrict__ Qt,  const u16* __restrict__ Kt, const u16* __restrict__ Vt,
    const float* __restrict__ b1, const float* __restrict__ b2,
    const float* __restrict__ qbv, const float* __restrict__ kbv, const float* __restrict__ vbv,
    float* __restrict__ emb,
    u16* __restrict__ Qb, u16* __restrict__ Kb, u16* __restrict__ Vb)
{
    __shared__ u16 hb[4][16 * 136];   // per-wave h tile, row stride 136 (pad 8)
    __shared__ u16 eb[4][16 * 72];    // per-wave emb tile, row stride 72
    const int tid = threadIdx.x, wave = tid >> 6, lane = tid & 63;
    const int m_ = lane & 15, quad = lane >> 4;

    int chunk = blockIdx.x;
    if (chunk >= NCHUNK) return;

    float4 cur[8];
    {
        const float4* xr = (const float4*)(X + (size_t)(chunk * 64 + wave * 16 + m_) * 128);
#pragma unroll
        for (int kk = 0; kk < 4; ++kk) {
            cur[2 * kk]     = xr[kk * 8 + quad * 2];
            cur[2 * kk + 1] = xr[kk * 8 + quad * 2 + 1];
        }
    }

    while (true) {
        int nextc = chunk + ENC_GRID;
        bool has_next = nextc < NCHUNK;
        float4 nxt[8];
        if (has_next) {
            const float4* xr = (const float4*)(X + (size_t)(nextc * 64 + wave * 16 + m_) * 128);
#pragma unroll
            for (int kk = 0; kk < 4; ++kk) {
                nxt[2 * kk]     = xr[kk * 8 + quad * 2];
                nxt[2 * kk + 1] = xr[kk * 8 + quad * 2 + 1];
            }
        }

        const int rbase = chunk * 64 + wave * 16;
        // convert current raw X -> bf16 A-fragments
        short8 ax[4];
#pragma unroll
        for (int kk = 0; kk < 4; ++kk) {
            float4 u = cur[2 * kk], v = cur[2 * kk + 1];
            short8 t;
            t[0] = (short)f2bf(u.x); t[1] = (short)f2bf(u.y);
            t[2] = (short)f2bf(u.z); t[3] = (short)f2bf(u.w);
            t[4] = (short)f2bf(v.x); t[5] = (short)f2bf(v.y);
            t[6] = (short)f2bf(v.z); t[7] = (short)f2bf(v.w);
            ax[kk] = t;
        }

        u16* hrow = &hb[wave][0];
        // ---- enc1: h = relu(X @ W1 + b1), 8 col-tiles of 16 ----
#pragma unroll
        for (int n0 = 0; n0 < 8; ++n0) {
            float bv = b1[n0 * 16 + m_];
            f32x4 acc = {bv, bv, bv, bv};
            const short8* w = (const short8*)(W1t + (size_t)(n0 * 16 + m_) * 128);
#pragma unroll
            for (int kk = 0; kk < 4; ++kk)
                acc = __builtin_amdgcn_mfma_f32_16x16x32_bf16(ax[kk], w[kk * 4 + quad], acc, 0, 0, 0);
#pragma unroll
            for (int r = 0; r < 4; ++r)
                hrow[(quad * 4 + r) * 136 + n0 * 16 + m_] = f2bf(fmaxf(acc[r], 0.f));
        }

        short8 ah[4];
#pragma unroll
        for (int kk = 0; kk < 4; ++kk)
            ah[kk] = *(const short8*)&hrow[m_ * 136 + kk * 32 + quad * 8];

        u16* erow = &eb[wave][0];
        // ---- enc2: emb = h @ W2 + b2 ----
#pragma unroll
        for (int n0 = 0; n0 < 4; ++n0) {
            float bv = b2[n0 * 16 + m_];
            f32x4 acc = {bv, bv, bv, bv};
            const short8* w = (const short8*)(W2t + (size_t)(n0 * 16 + m_) * 128);
#pragma unroll
            for (int kk = 0; kk < 4; ++kk)
                acc = __builtin_amdgcn_mfma_f32_16x16x32_bf16(ah[kk], w[kk * 4 + quad], acc, 0, 0, 0);
#pragma unroll
            for (int r = 0; r < 4; ++r) {
                float v = acc[r];
                emb[(size_t)(rbase + quad * 4 + r) * 64 + n0 * 16 + m_] = v;
                erow[(quad * 4 + r) * 72 + n0 * 16 + m_] = f2bf(v);
            }
        }

        short8 ae[2];
#pragma unroll
        for (int kk = 0; kk < 2; ++kk)
            ae[kk] = *(const short8*)&erow[m_ * 72 + kk * 32 + quad * 8];

        // ---- Q, K, V ----
        const u16*   Wt3[3] = {Qt, Kt, Vt};
        const float* Bb3[3] = {qbv, kbv, vbv};
        u16*         Ob3[3] = {Qb, Kb, Vb};
#pragma unroll
        for (int m3 = 0; m3 < 3; ++m3) {
            const u16* Wt = Wt3[m3];
            const float* bp = Bb3[m3];
            u16* O = Ob3[m3];
#pragma unroll
            for (int n0 = 0; n0 < 4; ++n0) {
                float bv = bp[n0 * 16 + m_];
                f32x4 acc = {bv, bv, bv, bv};
                const short8* w = (const short8*)(Wt + (size_t)(n0 * 16 + m_) * 64);
#pragma unroll
                for (int kk = 0; kk < 2; ++kk)
                    acc = __builtin_amdgcn_mfma_f32_16x16x32_bf16(ae[kk], w[kk * 4 + quad], acc, 0, 0, 0);
#pragma unroll
                for (int r = 0; r < 4; ++r)
                    O[(size_t)(rbase + quad * 4 + r) * 64 + n0 * 16 + m_] = f2bf(acc[r]);
            }
        }

        if (!has_next) break;
#pragma unroll
        for (int i = 0; i < 8; ++i) cur[i] = nxt[i];
        chunk = nextc;
    }
}

// ---------------- chem bucket: edges by dst (src lists) ----------------
__global__ __launch_bounds__(256) void chem_bucket(const int* __restrict__ chem,
                                                   int* __restrict__ cnt,
                                                   int* __restrict__ slist)
{
    for (int e = blockIdx.x * 256 + threadIdx.x; e < ECHEM; e += SC_GRID * 256) {
        int d = chem[ECHEM + e];
        int s = chem[e];
        int pos = atomicAdd(&cnt[d], 1);
        if (pos < CHEM_CAP) slist[d * CHEM_CAP + pos] = s;
    }
}

// ---------------- chem weighted sum, DST-MAJOR (wave-coherent gathers) ----------------
// Wave owns a dst; lane = column. Per edge: K row + V row = two coherent 128B gathers
// (2 cache lines each, vs 64 divergent lines in edge-major). Q read once per dst.
// Produces unnormalized T[d] = sum_e w_e * V[src_e] (bf16) and Zd[d] = sum_e w_e.
__global__ __launch_bounds__(256) void chem_wsum(const u16* __restrict__ Qb,
                                                 const u16* __restrict__ Kb,
                                                 const u16* __restrict__ Vb,
                                                 const int* __restrict__ cnt,
                                                 const int* __restrict__ slist,
                                                 u16* __restrict__ T,
                                                 float* __restrict__ Zd)
{
    const int wave = threadIdx.x >> 6, lane = threadIdx.x & 63;
    const int d0 = blockIdx.x * 16 + wave * 4;        // 4 dsts per wave
#pragma unroll 1
    for (int t = 0; t < 4; ++t) {
        int d = d0 + t;
        int c = cnt[d]; if (c > CHEM_CAP) c = CHEM_CAP;
        float q = bf2f(Qb[(size_t)d * 64 + lane]);
        int sv = (lane < c) ? slist[d * CHEM_CAP + lane] : 0;
        float accT = 0.f, zd = 0.f;
        int i = 0;
        for (; i + 2 <= c; i += 2) {                  // 2 edges interleaved: 4 loads in flight
            int s0 = __shfl(sv, i), s1 = __shfl(sv, i + 1);
            float k0 = bf2f(Kb[(size_t)s0 * 64 + lane]);
            float v0 = bf2f(Vb[(size_t)s0 * 64 + lane]);
            float k1 = bf2f(Kb[(size_t)s1 * 64 + lane]);
            float v1 = bf2f(Vb[(size_t)s1 * 64 + lane]);
            float p0 = q * k0, p1 = q * k1;
            p0 += __shfl_xor(p0, 1);  p1 += __shfl_xor(p1, 1);
            p0 += __shfl_xor(p0, 2);  p1 += __shfl_xor(p1, 2);
            p0 += __shfl_xor(p0, 4);  p1 += __shfl_xor(p1, 4);
            p0 += __shfl_xor(p0, 8);  p1 += __shfl_xor(p1, 8);
            p0 += __shfl_xor(p0, 16); p1 += __shfl_xor(p1, 16);
            p0 += __shfl_xor(p0, 32); p1 += __shfl_xor(p1, 32);
            float w0 = __expf(p0 * 0.125f), w1 = __expf(p1 * 0.125f);
            zd += w0 + w1;
            accT += w0 * v0 + w1 * v1;
        }
        if (i < c) {
            int s = __shfl(sv, i);
            float kc = bf2f(Kb[(size_t)s * 64 + lane]);
            float vc = bf2f(Vb[(size_t)s * 64 + lane]);
            float p = q * kc;
            p += __shfl_xor(p, 1);  p += __shfl_xor(p, 2);
            p += __shfl_xor(p, 4);  p += __shfl_xor(p, 8);
            p += __shfl_xor(p, 16); p += __shfl_xor(p, 32);
            float w = __expf(p * 0.125f);
            zd += w; accT += w * vc;
        }
        T[(size_t)d * 64 + lane] = f2bf(accT);        // coalesced 128B row
        if (lane == 0) Zd[d] = zd;
    }
}

// ---------------- Z reduction: Zp = sum(Zd) ----------------
__global__ __launch_bounds__(256) void zred(const float* __restrict__ Zd,
                                            float* __restrict__ Zp)
{
    __shared__ float wsum[4];
    float s = 0.f;
    for (int i = blockIdx.x * 256 + threadIdx.x; i < NP; i += 256 * 256)
        s += Zd[i];
    for (int off = 1; off < 64; off <<= 1) s += __shfl_xor(s, off);
    if ((threadIdx.x & 63) == 0) wsum[threadIdx.x >> 6] = s;
    __syncthreads();
    if (threadIdx.x == 0) atomicAdd(Zp, wsum[0] + wsum[1] + wsum[2] + wsum[3]);
}

// ---------------- chem finalize + msg GEMM: Mp = relu((emb + T/Z) @ msg_w + b) ----------------
// Pure streaming now (no gathers) + per-wave MFMA; coalesced Mpb stores.
__global__ __launch_bounds__(256) void chem_fin_msg(const float* __restrict__ emb,
                                                    const u16* __restrict__ T,
                                                    const float* __restrict__ Zp,
                                                    const u16* __restrict__ Msgt,
                                                    const float* __restrict__ mb,
                                                    u16* __restrict__ Mpb)
{
    __shared__ u16 eb[4][16 * 72];
    const int tid = threadIdx.x, wave = tid >> 6, lane = tid & 63;
    const int m_ = lane & 15, quad = lane >> 4;
    const int d0 = blockIdx.x * 64 + wave * 16;
    const int srow = lane >> 3, scol = (lane & 7) * 8;
    const float invZ = 1.f / Zp[0];
    u16* erow = &eb[wave][0];
#pragma unroll
    for (int t = 0; t < 16; ++t) {
        int d = d0 + t;
        float v = emb[(size_t)d * 64 + lane] + bf2f(T[(size_t)d * 64 + lane]) * invZ;
        erow[t * 72 + lane] = f2bf(v);
    }
    short8 a0 = *(const short8*)&erow[m_ * 72 + quad * 8];
    short8 a1 = *(const short8*)&erow[m_ * 72 + 32 + quad * 8];
#pragma unroll
    for (int n0 = 0; n0 < 4; ++n0) {
        float bv = mb[n0 * 16 + m_];
        f32x4 acc = {bv, bv, bv, bv};
        const short8* w = (const short8*)(Msgt + (size_t)(n0 * 16 + m_) * 64);
        acc = __builtin_amdgcn_mfma_f32_16x16x32_bf16(a0, w[quad], acc, 0, 0, 0);
        acc = __builtin_amdgcn_mfma_f32_16x16x32_bf16(a1, w[4 + quad], acc, 0, 0, 0);
#pragma unroll
        for (int r = 0; r < 4; ++r)
            erow[(quad * 4 + r) * 72 + n0 * 16 + m_] = f2bf(fmaxf(acc[r], 0.f));
    }
    short8 r0 = *(const short8*)&erow[srow * 72 + scol];
    short8 r1 = *(const short8*)&erow[(srow + 8) * 72 + scol];
    *(short8*)(Mpb + (size_t)(d0 + srow) * 64 + scol) = r0;
    *(short8*)(Mpb + (size_t)(d0 + 8 + srow) * 64 + scol) = r1;
}

// ---------------- p2p bucket: two-phase LDS histogram ----------------
__global__ __launch_bounds__(256) void p2p_bucket(const int* __restrict__ p2p,
                                                  int* __restrict__ cnt,
                                                  int* __restrict__ list)
{
    __shared__ int lhist[NPOS];
    __shared__ int lbase[NPOS];
    int tid = threadIdx.x;
    for (int i = tid; i < NPOS; i += 256) lhist[i] = 0;
    __syncthreads();
    const int chunk = (EP2P + PB_BLOCKS - 1) / PB_BLOCKS;   // 6250
    int e0 = blockIdx.x * chunk;
    int e1 = e0 + chunk; if (e1 > EP2P) e1 = EP2P;
    for (int e = e0 + tid; e < e1; e += 256)
        atomicAdd(&lhist[p2p[EP2P + e]], 1);
    __syncthreads();
    for (int i = tid; i < NPOS; i += 256) {
        lbase[i] = atomicAdd(&cnt[i], lhist[i]);
        lhist[i] = 0;
    }
    __syncthreads();
    for (int e = e0 + tid; e < e1; e += 256) {
        int d = p2p[EP2P + e];
        int p = lbase[d] + atomicAdd(&lhist[d], 1);
        if (p < P2P_CAP) list[d * P2P_CAP + p] = p2p[e];
    }
}

// ---------------- p2p segment-sum of Mp (bf16), split per dst, 4-way unrolled gather ----------------
__global__ __launch_bounds__(256) void p2p_agg(const u16* __restrict__ Mpb,
                                               const int* __restrict__ cnt,
                                               const int* __restrict__ list,
                                               float* __restrict__ pos_agg)
{
    __shared__ float part[4 * 64];
    int d = blockIdx.x >> 3;                 // / AGG_SPLIT
    int sp = blockIdx.x & (AGG_SPLIT - 1);
    int wave = threadIdx.x >> 6, lane = threadIdx.x & 63;
    int c = cnt[d];
    int cl = c > P2P_CAP ? P2P_CAP : c;
    int seg = (cl + AGG_SPLIT - 1) / AGG_SPLIT;
    int i0b = sp * seg;
    int i1 = i0b + seg; if (i1 > cl) i1 = cl;
    float acc = 0.f;
    for (int i0 = i0b + wave * 64; i0 < i1; i0 += 256) {
        int n = i1 - i0; if (n > 64) n = 64;
        int sv = (lane < n) ? list[d * P2P_CAP + i0 + lane] : 0;
        int i = 0;
        for (; i + 4 <= n; i += 4) {
            int s0 = __shfl(sv, i),     s1 = __shfl(sv, i + 1);
            int s2 = __shfl(sv, i + 2), s3 = __shfl(sv, i + 3);
            float v0 = bf2f(Mpb[(size_t)s0 * 64 + lane]);
            float v1 = bf2f(Mpb[(size_t)s1 * 64 + lane]);
            float v2 = bf2f(Mpb[(size_t)s2 * 64 + lane]);
            float v3 = bf2f(Mpb[(size_t)s3 * 64 + lane]);
            acc += v0 + v1 + v2 + v3;
        }
        for (; i < n; ++i) {
            int s = __shfl(sv, i);
            acc += bf2f(Mpb[(size_t)s * 64 + lane]);
        }
    }
    part[wave * 64 + lane] = acc;
    __syncthreads();
    if (wave == 0) {
        float t = part[lane] + part[64 + lane] + part[128 + lane] + part[192 + lane];
        atomicAdd(&pos_agg[d * 64 + lane], t);
    }
}

// ---------------- fused: 3 position-update rounds + p2t message GEMM (row-local) ----------------
__global__ __launch_bounds__(256) void pos_rounds(const float* __restrict__ pos0,
                                                  const float* __restrict__ agg,   // raw sums
                                                  const int* __restrict__ cnt,
                                                  const float* __restrict__ upd_w, // 128x64
                                                  const float* __restrict__ upd_b,
                                                  const float* __restrict__ msg_w, // 64x64
                                                  const float* __restrict__ msg_b,
                                                  float* __restrict__ Mt)          // 320x64
{
    __shared__ float cur[4][64], nxt[4][64], aggw[4][64];
    int tid = threadIdx.x;
    int r = tid >> 6, j = tid & 63;
    int row = blockIdx.x * 4 + r;
    int c = cnt[row];
    float invc = 1.f / (float)(c < 1 ? 1 : c);
    float aw = 0.f;
    const float* ar = agg + row * 64;
#pragma unroll 8
    for (int k = 0; k < 64; ++k) aw += ar[k] * upd_w[(64 + k) * 64 + j];
    aggw[r][j] = aw * invc + upd_b[j];
    cur[r][j] = pos0[row * 64 + j];
    __syncthreads();
#pragma unroll 1
    for (int round = 0; round < 3; ++round) {
        float acc = aggw[r][j];
#pragma unroll 8
        for (int k = 0; k < 64; ++k) acc += cur[r][k] * upd_w[k * 64 + j];
        nxt[r][j] = fmaxf(acc, 0.f);
        __syncthreads();
        cur[r][j] = nxt[r][j];
        __syncthreads();
    }
    float acc = msg_b[j];
#pragma unroll 8
    for (int k = 0; k < 64; ++k) acc += cur[r][k] * msg_w[k * 64 + j];
    Mt[row * 64 + j] = fmaxf(acc, 0.f);
}

// ---------------- p2t team rounds + game head (single block) ----------------
__global__ __launch_bounds__(256) void p2t_head(
    const float* __restrict__ Mt,
    const int* __restrict__ p2t_edges,
    const float* __restrict__ upd_w, const float* __restrict__ upd_b,
    const int* __restrict__ team_indices,
    const float* __restrict__ team_table,
    const int* __restrict__ home_p, const int* __restrict__ away_p,
    const float* __restrict__ gp_w1, const float* __restrict__ gp_b1,
    const float* __restrict__ gp_w2, const float* __restrict__ gp_b2,
    const float* __restrict__ gp_w3, const float* __restrict__ gp_b3,
    float* __restrict__ out)
{
    __shared__ int   tcnt[NT];
    __shared__ int   tlist[NT * T2_CAP];
    __shared__ float aggbar[NT * 64];
    __shared__ float teamA[NT * 64];
    __shared__ float teamB[NT * 64];
    __shared__ float z1[128];
    __shared__ float z2[64];
    int tid = threadIdx.x;

    if (tid < NT) tcnt[tid] = 0;
    __syncthreads();
    for (int e = tid; e < EP2T; e += 256) {
        int s = p2t_edges[e], d = p2t_edges[EP2T + e];
        int p = atomicAdd(&tcnt[d], 1);
        if (p < T2_CAP) tlist[d * T2_CAP + p] = s;
    }
    __syncthreads();
    for (int i = tid; i < NT * 64; i += 256) {
        int d = i >> 6, c = i & 63;
        int cn = tcnt[d];
        int cl = cn > T2_CAP ? T2_CAP : cn;
        float acc = 0.f;
        for (int j = 0; j < cl; ++j) acc += Mt[tlist[d * T2_CAP + j] * 64 + c];
        float dv = cn < 1 ? 1.f : (float)cn;
        aggbar[i] = acc / dv;
        teamA[i] = team_table[team_indices[d] * 64 + c];
    }
    __syncthreads();

    float* tin = teamA; float* tout = teamB;
    for (int round = 0; round < 3; ++round) {
        for (int i = tid; i < NT * 64; i += 256) {
            int r = i >> 6, j = i & 63;
            float acc = upd_b[j];
            for (int k = 0; k < 64; ++k) acc += tin[r * 64 + k] * upd_w[k * 64 + j];
            for (int k = 0; k < 64; ++k) acc += aggbar[r * 64 + k] * upd_w[(64 + k) * 64 + j];
            tout[i] = fmaxf(acc, 0.f);
        }
        __syncthreads();
        float* tmp = tin; tin = tout; tout = tmp;
    }

    int home = home_p[0], away = away_p[0];
    if (tid < 128) {
        float acc = gp_b1[tid];
        for (int k = 0; k < 128; ++k) {
            float g = (k < 64) ? tin[home * 64 + k] : tin[away * 64 + (k - 64)];
            acc += g * gp_w1[k * 128 + tid];
        }
        z1[tid] = fmaxf(acc, 0.f);
    }
    __syncthreads();
    if (tid < 64) {
        float acc = gp_b2[tid];
        for (int k = 0; k < 128; ++k) acc += z1[k] * gp_w2[k * 64 + tid];
        z2[tid] = fmaxf(acc, 0.f);
    }
    __syncthreads();
    if (tid == 0) {
        float acc = gp_b3[0];
        for (int k = 0; k < 64; ++k) acc += z2[k] * gp_w3[k];
        out[0] = 1.f / (1.f + __expf(-acc));
    }
}

// ---------------- host launcher ----------------
extern "C" void kernel_launch(void* const* d_in, const int* in_sizes, int n_in,
                              void* d_out, int out_size, void* d_ws, size_t ws_size,
                              hipStream_t stream)
{
    const float* X        = (const float*)d_in[0];
    const int*   pos_idx  = (const int*)d_in[1];
    const int*   team_idx = (const int*)d_in[2];
    const int*   p2p      = (const int*)d_in[3];
    const int*   p2t      = (const int*)d_in[4];
    const int*   chem     = (const int*)d_in[5];
    const int*   home_p   = (const int*)d_in[6];
    const int*   away_p   = (const int*)d_in[7];
    const float* enc_w1   = (const float*)d_in[8];
    const float* enc_b1   = (const float*)d_in[9];
    const float* enc_w2   = (const float*)d_in[10];
    const float* enc_b2   = (const float*)d_in[11];
    const float* pos_tab  = (const float*)d_in[12];
    const float* team_tab = (const float*)d_in[13];
    const float* q_w = (const float*)d_in[14]; const float* q_b = (const float*)d_in[15];
    const float* k_w = (const float*)d_in[16]; const float* k_b = (const float*)d_in[17];
    const float* v_w = (const float*)d_in[18]; const float* v_b = (const float*)d_in[19];
    const float* p2p_msg_w = (const float*)d_in[20]; const float* p2p_msg_b = (const float*)d_in[21];
    const float* p2p_upd_w = (const float*)d_in[22]; const float* p2p_upd_b = (const float*)d_in[23];
    const float* p2t_msg_w = (const float*)d_in[24]; const float* p2t_msg_b = (const float*)d_in[25];
    const float* p2t_upd_w = (const float*)d_in[26]; const float* p2t_upd_b = (const float*)d_in[27];
    const float* gp_w1 = (const float*)d_in[28]; const float* gp_b1 = (const float*)d_in[29];
    const float* gp_w2 = (const float*)d_in[30]; const float* gp_b2 = (const float*)d_in[31];
    const float* gp_w3 = (const float*)d_in[32]; const float* gp_b3 = (const float*)d_in[33];
    float* out = (float*)d_out;

    // ---- workspace layout (bytes), peak ~209.4 MB ----
    char* ws = (char*)d_ws;
    int*      slist     = (int*)  (ws + 0);            // NP*32*4 = 25.6MB
    u16*      T         = (u16*)  (ws + 25600000);     // NP*64 bf16 = 25.6MB
    float*    emb       = (float*)(ws + 51200000);     // NP*64 fp32 = 51.2MB
    u16*      Qb        = (u16*)  (ws + 102400000);
    u16*      Kb        = (u16*)  (ws + 128000000);
    u16*      Vb        = (u16*)  (ws + 153600000);
    u16*      Mpb       = (u16*)  (ws + 179200000);
    int*      p2p_list  = (int*)  (ws + 204800000);    // 2.62MB
    int*      chem_cnt  = (int*)  (ws + 207421440);    // 800KB
    float*    Zd        = (float*)(ws + 208221440);    // 800KB
    int*      p2p_cnt   = (int*)  (ws + 209021440);
    float*    pos_agg   = (float*)(ws + 209022720);
    float*    posA      = (float*)(ws + 209104640);
    float*    Mt        = (float*)(ws + 209186560);
    float*    Zp        = (float*)(ws + 209268480);
    u16*      Wpack     = (u16*)  (ws + 209268496);    // 80KB transposed bf16 weights
    u16* W1t  = Wpack;
    u16* W2t  = Wpack + 16384;
    u16* Qt   = Wpack + 24576;
    u16* Kt   = Wpack + 28672;
    u16* Vt   = Wpack + 32768;
    u16* Msgt = Wpack + 36864;

    const int NB_NP = (NP + 255) / 256;

    hipLaunchKernelGGL(init_kernel, dim3(NB_NP), dim3(256), 0, stream,
                       chem_cnt, p2p_cnt, Zp, pos_idx, pos_tab, posA, pos_agg,
                       enc_w1, enc_w2, q_w, k_w, v_w, p2p_msg_w, Wpack);
    // chem edge bucketing (independent of enc)
    hipLaunchKernelGGL(chem_bucket, dim3(SC_GRID), dim3(256), 0, stream, chem, chem_cnt, slist);
    // fused encoder + QKV (persistent, prefetched)
    hipLaunchKernelGGL(mfma_enc, dim3(ENC_GRID), dim3(256), 0, stream,
                       X, W1t, W2t, Qt, Kt, Vt,
                       enc_b1, enc_b2, q_b, k_b, v_b,
                       emb, Qb, Kb, Vb);
    // dst-major attention weighted sum (coherent gathers)
    hipLaunchKernelGGL(chem_wsum, dim3(NP / 16), dim3(256), 0, stream,
                       Qb, Kb, Vb, chem_cnt, slist, T, Zd);
    hipLaunchKernelGGL(zred, dim3(256), dim3(256), 0, stream, Zd, Zp);
    // finalize + p2p message GEMM (streaming)
    hipLaunchKernelGGL(chem_fin_msg, dim3(NP / 64), dim3(256), 0, stream,
                       emb, T, Zp, Msgt, p2p_msg_b, Mpb);
    // p2p phase
    hipLaunchKernelGGL(p2p_bucket, dim3(PB_BLOCKS), dim3(256), 0, stream, p2p, p2p_cnt, p2p_list);
    hipLaunchKernelGGL(p2p_agg, dim3(NPOS * AGG_SPLIT), dim3(256), 0, stream,
                       Mpb, p2p_cnt, p2p_list, pos_agg);
    hipLaunchKernelGGL(pos_rounds, dim3(NPOS / 4), dim3(256), 0, stream,
                       posA, pos_agg, p2p_cnt, p2p_upd_w, p2p_upd_b,
                       p2t_msg_w, p2t_msg_b, Mt);
    hipLaunchKernelGGL(p2t_head, dim3(1), dim3(256), 0, stream,
                       Mt, p2t, p2t_upd_w, p2t_upd_b, team_idx, team_tab, home_p, away_p,
                       gp_w1, gp_b1, gp_w2, gp_b2, gp_w3, gp_b3, out);
}

// Round 9
// 568.527 us; speedup vs baseline: 1.3228x; 1.0434x over previous
//
#include <hip/hip_runtime.h>
#include <hip/hip_bf16.h>

// ---------------- problem constants ----------------
#define NP     200000
#define NPOS   320
#define NT     32
#define FEAT   128
#define EMB    64
#define HID    128
#define EP2P   400000
#define EP2T   640
#define ECHEM  1000000

#define CHEM_CAP 32
#define P2P_CAP  2048
#define T2_CAP   64
#define SC_GRID  2048
#define PB_BLOCKS 64
#define AGG_SPLIT 8
#define ENC_GRID 1024
#define NCHUNK   (NP / 64)    // 3125

typedef unsigned short u16;
typedef __attribute__((ext_vector_type(8))) short short8;   // 8 bf16 = 4 VGPRs
typedef __attribute__((ext_vector_type(4))) float f32x4;

static __device__ inline u16 f2bf(float f) {               // RNE fp32->bf16
    unsigned u = __float_as_uint(f);
    return (u16)((u + 0x7fffu + ((u >> 16) & 1u)) >> 16);
}
static __device__ inline float bf2f(u16 h) {
    return __uint_as_float(((unsigned)h) << 16);
}
static __device__ inline float bprod(unsigned a, unsigned b) {  // dot of 2 packed bf16 pairs
    float a0 = __uint_as_float(a << 16), a1 = __uint_as_float(a & 0xffff0000u);
    float b0 = __uint_as_float(b << 16), b1 = __uint_as_float(b & 0xffff0000u);
    return fmaf(a0, b0, a1 * b1);
}

// ---------------- init: counters, pos embeds, pos_agg zero, weight transpose->bf16 ----------------
__global__ __launch_bounds__(256) void init_kernel(int* __restrict__ chem_cnt,
                                                   int* __restrict__ p2p_cnt,
                                                   float* __restrict__ Zp,
                                                   const int* __restrict__ pos_idx,
                                                   const float* __restrict__ pos_table,
                                                   float* __restrict__ pos0,
                                                   float* __restrict__ pos_agg,
                                                   const float* __restrict__ w1,
                                                   const float* __restrict__ w2,
                                                   const float* __restrict__ qw,
                                                   const float* __restrict__ kw,
                                                   const float* __restrict__ vw,
                                                   const float* __restrict__ mw,
                                                   u16* __restrict__ Wpack)
{
    int t = blockIdx.x * 256 + threadIdx.x;
    if (t < NP) chem_cnt[t] = 0;
    if (t < NPOS) p2p_cnt[t] = 0;
    if (t < NPOS * EMB) {
        pos0[t] = pos_table[pos_idx[t >> 6] * EMB + (t & 63)];
        pos_agg[t] = 0.f;
    }
    if (t == 0) *Zp = 0.f;
    if (t < 40960) {
        float v;
        if (t < 16384)        { int i = t;         v = w1[(i & 127) * 128 + (i >> 7)]; }
        else if (t < 24576)   { int i = t - 16384; v = w2[(i & 127) * 64  + (i >> 7)]; }
        else if (t < 28672)   { int i = t - 24576; v = qw[(i & 63) * 64 + (i >> 6)]; }
        else if (t < 32768)   { int i = t - 28672; v = kw[(i & 63) * 64 + (i >> 6)]; }
        else if (t < 36864)   { int i = t - 32768; v = vw[(i & 63) * 64 + (i >> 6)]; }
        else                  { int i = t - 36864; v = mw[(i & 63) * 64 + (i >> 6)]; }
        Wpack[t] = f2bf(v);
    }
}

// ---------------- fused MFMA encoder: persistent grid + raw-X prefetch of next chunk ----------------
__global__ __launch_bounds__(256) void mfma_enc(
    const float* __restrict__ X,
    const u16* __restrict__ W1t, const u16* __restrict__ W2t,
    const u16* __restrict__ Qt,  const u16* __restrict__ Kt, const u16* __restrict__ Vt,
    const float* __restrict__ b1, const float* __restrict__ b2,
    const float* __restrict__ qbv, const float* __restrict__ kbv, const float* __restrict__ vbv,
    float* __restrict__ emb,
    u16* __restrict__ Qb, u16* __restrict__ Kb, u16* __restrict__ Vb)
{
    __shared__ u16 hb[4][16 * 136];   // per-wave h tile, row stride 136 (pad 8)
    __shared__ u16 eb[4][16 * 72];    // per-wave emb tile, row stride 72
    const int tid = threadIdx.x, wave = tid >> 6, lane = tid & 63;
    const int m_ = lane & 15, quad = lane >> 4;

    int chunk = blockIdx.x;
    if (chunk >= NCHUNK) return;

    float4 cur[8];
    {
        const float4* xr = (const float4*)(X + (size_t)(chunk * 64 + wave * 16 + m_) * 128);
#pragma unroll
        for (int kk = 0; kk < 4; ++kk) {
            cur[2 * kk]     = xr[kk * 8 + quad * 2];
            cur[2 * kk + 1] = xr[kk * 8 + quad * 2 + 1];
        }
    }

    while (true) {
        int nextc = chunk + ENC_GRID;
        bool has_next = nextc < NCHUNK;
        float4 nxt[8];
        if (has_next) {
            const float4* xr = (const float4*)(X + (size_t)(nextc * 64 + wave * 16 + m_) * 128);
#pragma unroll
            for (int kk = 0; kk < 4; ++kk) {
                nxt[2 * kk]     = xr[kk * 8 + quad * 2];
                nxt[2 * kk + 1] = xr[kk * 8 + quad * 2 + 1];
            }
        }

        const int rbase = chunk * 64 + wave * 16;
        short8 ax[4];
#pragma unroll
        for (int kk = 0; kk < 4; ++kk) {
            float4 u = cur[2 * kk], v = cur[2 * kk + 1];
            short8 t;
            t[0] = (short)f2bf(u.x); t[1] = (short)f2bf(u.y);
            t[2] = (short)f2bf(u.z); t[3] = (short)f2bf(u.w);
            t[4] = (short)f2bf(v.x); t[5] = (short)f2bf(v.y);
            t[6] = (short)f2bf(v.z); t[7] = (short)f2bf(v.w);
            ax[kk] = t;
        }

        u16* hrow = &hb[wave][0];
#pragma unroll
        for (int n0 = 0; n0 < 8; ++n0) {
            float bv = b1[n0 * 16 + m_];
            f32x4 acc = {bv, bv, bv, bv};
            const short8* w = (const short8*)(W1t + (size_t)(n0 * 16 + m_) * 128);
#pragma unroll
            for (int kk = 0; kk < 4; ++kk)
                acc = __builtin_amdgcn_mfma_f32_16x16x32_bf16(ax[kk], w[kk * 4 + quad], acc, 0, 0, 0);
#pragma unroll
            for (int r = 0; r < 4; ++r)
                hrow[(quad * 4 + r) * 136 + n0 * 16 + m_] = f2bf(fmaxf(acc[r], 0.f));
        }

        short8 ah[4];
#pragma unroll
        for (int kk = 0; kk < 4; ++kk)
            ah[kk] = *(const short8*)&hrow[m_ * 136 + kk * 32 + quad * 8];

        u16* erow = &eb[wave][0];
#pragma unroll
        for (int n0 = 0; n0 < 4; ++n0) {
            float bv = b2[n0 * 16 + m_];
            f32x4 acc = {bv, bv, bv, bv};
            const short8* w = (const short8*)(W2t + (size_t)(n0 * 16 + m_) * 128);
#pragma unroll
            for (int kk = 0; kk < 4; ++kk)
                acc = __builtin_amdgcn_mfma_f32_16x16x32_bf16(ah[kk], w[kk * 4 + quad], acc, 0, 0, 0);
#pragma unroll
            for (int r = 0; r < 4; ++r) {
                float v = acc[r];
                emb[(size_t)(rbase + quad * 4 + r) * 64 + n0 * 16 + m_] = v;
                erow[(quad * 4 + r) * 72 + n0 * 16 + m_] = f2bf(v);
            }
        }

        short8 ae[2];
#pragma unroll
        for (int kk = 0; kk < 2; ++kk)
            ae[kk] = *(const short8*)&erow[m_ * 72 + kk * 32 + quad * 8];

        const u16*   Wt3[3] = {Qt, Kt, Vt};
        const float* Bb3[3] = {qbv, kbv, vbv};
        u16*         Ob3[3] = {Qb, Kb, Vb};
#pragma unroll
        for (int m3 = 0; m3 < 3; ++m3) {
            const u16* Wt = Wt3[m3];
            const float* bp = Bb3[m3];
            u16* O = Ob3[m3];
#pragma unroll
            for (int n0 = 0; n0 < 4; ++n0) {
                float bv = bp[n0 * 16 + m_];
                f32x4 acc = {bv, bv, bv, bv};
                const short8* w = (const short8*)(Wt + (size_t)(n0 * 16 + m_) * 64);
#pragma unroll
                for (int kk = 0; kk < 2; ++kk)
                    acc = __builtin_amdgcn_mfma_f32_16x16x32_bf16(ae[kk], w[kk * 4 + quad], acc, 0, 0, 0);
#pragma unroll
                for (int r = 0; r < 4; ++r)
                    O[(size_t)(rbase + quad * 4 + r) * 64 + n0 * 16 + m_] = f2bf(acc[r]);
            }
        }

        if (!has_next) break;
#pragma unroll
        for (int i = 0; i < 8; ++i) cur[i] = nxt[i];
        chunk = nextc;
    }
}

// ---------------- chem bucket: edges by dst (src lists) ----------------
__global__ __launch_bounds__(256) void chem_bucket(const int* __restrict__ chem,
                                                   int* __restrict__ cnt,
                                                   int* __restrict__ slist)
{
    for (int e = blockIdx.x * 256 + threadIdx.x; e < ECHEM; e += SC_GRID * 256) {
        int d = chem[ECHEM + e];
        int s = chem[e];
        int pos = atomicAdd(&cnt[d], 1);
        if (pos < CHEM_CAP) slist[d * CHEM_CAP + pos] = s;
    }
}

// ---------------- chem weighted sum v2: 4 cols/lane, quarter-wave per edge ----------------
// Lane holds 4 columns (uint2 = 4 bf16); 16 lanes cover a 128B row; wave processes 4 edges
// per K/V load instruction. Score reduction: 4 shfl steps over 16 lanes, 4 edges at once.
// Outputs unnormalized T[d] = sum w*V[src] (bf16) and Zd[d] = sum w.
__global__ __launch_bounds__(256) void chem_wsum(const u16* __restrict__ Qb,
                                                 const u16* __restrict__ Kb,
                                                 const u16* __restrict__ Vb,
                                                 const int* __restrict__ cnt,
                                                 const int* __restrict__ slist,
                                                 u16* __restrict__ T,
                                                 float* __restrict__ Zd)
{
    const int wave = threadIdx.x >> 6, lane = threadIdx.x & 63;
    const int qid = lane >> 4, ql = lane & 15;      // quarter id, lane-in-quarter
    const int d0 = blockIdx.x * 16 + wave * 4;      // 4 dsts per wave
#pragma unroll 1
    for (int t = 0; t < 4; ++t) {
        int d = d0 + t;
        int c = cnt[d]; if (c > CHEM_CAP) c = CHEM_CAP;
        uint2 qv = *(const uint2*)(Qb + (size_t)d * 64 + ql * 4);
        int sv = (lane < c) ? slist[d * CHEM_CAP + lane] : 0;
        float a0 = 0.f, a1 = 0.f, a2 = 0.f, a3 = 0.f, zd = 0.f;
#pragma unroll 1
        for (int i = 0; i < c; i += 4) {
            int ei = i + qid;                        // <= 34 < 64: shfl index safe
            int s = __shfl(sv, ei);                  // lanes >= c hold 0 -> safe row
            uint2 kv = *(const uint2*)(Kb + (size_t)s * 64 + ql * 4);
            uint2 vv = *(const uint2*)(Vb + (size_t)s * 64 + ql * 4);
            float p = bprod(kv.x, qv.x) + bprod(kv.y, qv.y);
            p += __shfl_xor(p, 1);
            p += __shfl_xor(p, 2);
            p += __shfl_xor(p, 4);
            p += __shfl_xor(p, 8);                   // all 16 lanes of quarter have score
            float w = (ei < c) ? __expf(p * 0.125f) : 0.f;
            zd += w;
            a0 += w * bf2f((u16)(vv.x & 0xffffu));
            a1 += w * bf2f((u16)(vv.x >> 16));
            a2 += w * bf2f((u16)(vv.y & 0xffffu));
            a3 += w * bf2f((u16)(vv.y >> 16));
        }
        // combine quarters (same columns live at lane^16, lane^32)
        a0 += __shfl_xor(a0, 16); a0 += __shfl_xor(a0, 32);
        a1 += __shfl_xor(a1, 16); a1 += __shfl_xor(a1, 32);
        a2 += __shfl_xor(a2, 16); a2 += __shfl_xor(a2, 32);
        a3 += __shfl_xor(a3, 16); a3 += __shfl_xor(a3, 32);
        zd += __shfl_xor(zd, 16); zd += __shfl_xor(zd, 32);
        if (qid == 0) {
            uint2 o;
            o.x = (unsigned)f2bf(a0) | ((unsigned)f2bf(a1) << 16);
            o.y = (unsigned)f2bf(a2) | ((unsigned)f2bf(a3) << 16);
            *(uint2*)(T + (size_t)d * 64 + ql * 4) = o;
            if (ql == 0) Zd[d] = zd;
        }
    }
}

// ---------------- Z reduction: Zp = sum(Zd) ----------------
__global__ __launch_bounds__(256) void zred(const float* __restrict__ Zd,
                                            float* __restrict__ Zp)
{
    __shared__ float wsum[4];
    float s = 0.f;
    for (int i = blockIdx.x * 256 + threadIdx.x; i < NP; i += 256 * 256)
        s += Zd[i];
    for (int off = 1; off < 64; off <<= 1) s += __shfl_xor(s, off);
    if ((threadIdx.x & 63) == 0) wsum[threadIdx.x >> 6] = s;
    __syncthreads();
    if (threadIdx.x == 0) atomicAdd(Zp, wsum[0] + wsum[1] + wsum[2] + wsum[3]);
}

// ---------------- chem finalize + msg GEMM: Mp = relu((emb + T/Z) @ msg_w + b) ----------------
__global__ __launch_bounds__(256) void chem_fin_msg(const float* __restrict__ emb,
                                                    const u16* __restrict__ T,
                                                    const float* __restrict__ Zp,
                                                    const u16* __restrict__ Msgt,
                                                    const float* __restrict__ mb,
                                                    u16* __restrict__ Mpb)
{
    __shared__ u16 eb[4][16 * 72];
    const int tid = threadIdx.x, wave = tid >> 6, lane = tid & 63;
    const int m_ = lane & 15, quad = lane >> 4;
    const int d0 = blockIdx.x * 64 + wave * 16;
    const int srow = lane >> 3, scol = (lane & 7) * 8;
    const float invZ = 1.f / Zp[0];
    u16* erow = &eb[wave][0];
#pragma unroll
    for (int t = 0; t < 16; ++t) {
        int d = d0 + t;
        float v = emb[(size_t)d * 64 + lane] + bf2f(T[(size_t)d * 64 + lane]) * invZ;
        erow[t * 72 + lane] = f2bf(v);
    }
    short8 a0 = *(const short8*)&erow[m_ * 72 + quad * 8];
    short8 a1 = *(const short8*)&erow[m_ * 72 + 32 + quad * 8];
#pragma unroll
    for (int n0 = 0; n0 < 4; ++n0) {
        float bv = mb[n0 * 16 + m_];
        f32x4 acc = {bv, bv, bv, bv};
        const short8* w = (const short8*)(Msgt + (size_t)(n0 * 16 + m_) * 64);
        acc = __builtin_amdgcn_mfma_f32_16x16x32_bf16(a0, w[quad], acc, 0, 0, 0);
        acc = __builtin_amdgcn_mfma_f32_16x16x32_bf16(a1, w[4 + quad], acc, 0, 0, 0);
#pragma unroll
        for (int r = 0; r < 4; ++r)
            erow[(quad * 4 + r) * 72 + n0 * 16 + m_] = f2bf(fmaxf(acc[r], 0.f));
    }
    short8 r0 = *(const short8*)&erow[srow * 72 + scol];
    short8 r1 = *(const short8*)&erow[(srow + 8) * 72 + scol];
    *(short8*)(Mpb + (size_t)(d0 + srow) * 64 + scol) = r0;
    *(short8*)(Mpb + (size_t)(d0 + 8 + srow) * 64 + scol) = r1;
}

// ---------------- p2p bucket: two-phase LDS histogram ----------------
__global__ __launch_bounds__(256) void p2p_bucket(const int* __restrict__ p2p,
                                                  int* __restrict__ cnt,
                                                  int* __restrict__ list)
{
    __shared__ int lhist[NPOS];
    __shared__ int lbase[NPOS];
    int tid = threadIdx.x;
    for (int i = tid; i < NPOS; i += 256) lhist[i] = 0;
    __syncthreads();
    const int chunk = (EP2P + PB_BLOCKS - 1) / PB_BLOCKS;   // 6250
    int e0 = blockIdx.x * chunk;
    int e1 = e0 + chunk; if (e1 > EP2P) e1 = EP2P;
    for (int e = e0 + tid; e < e1; e += 256)
        atomicAdd(&lhist[p2p[EP2P + e]], 1);
    __syncthreads();
    for (int i = tid; i < NPOS; i += 256) {
        lbase[i] = atomicAdd(&cnt[i], lhist[i]);
        lhist[i] = 0;
    }
    __syncthreads();
    for (int e = e0 + tid; e < e1; e += 256) {
        int d = p2p[EP2P + e];
        int p = lbase[d] + atomicAdd(&lhist[d], 1);
        if (p < P2P_CAP) list[d * P2P_CAP + p] = p2p[e];
    }
}

// ---------------- p2p segment-sum of Mp (bf16), split per dst, 4-way unrolled gather ----------------
__global__ __launch_bounds__(256) void p2p_agg(const u16* __restrict__ Mpb,
                                               const int* __restrict__ cnt,
                                               const int* __restrict__ list,
                                               float* __restrict__ pos_agg)
{
    __shared__ float part[4 * 64];
    int d = blockIdx.x >> 3;                 // / AGG_SPLIT
    int sp = blockIdx.x & (AGG_SPLIT - 1);
    int wave = threadIdx.x >> 6, lane = threadIdx.x & 63;
    int c = cnt[d];
    int cl = c > P2P_CAP ? P2P_CAP : c;
    int seg = (cl + AGG_SPLIT - 1) / AGG_SPLIT;
    int i0b = sp * seg;
    int i1 = i0b + seg; if (i1 > cl) i1 = cl;
    float acc = 0.f;
    for (int i0 = i0b + wave * 64; i0 < i1; i0 += 256) {
        int n = i1 - i0; if (n > 64) n = 64;
        int sv = (lane < n) ? list[d * P2P_CAP + i0 + lane] : 0;
        int i = 0;
        for (; i + 4 <= n; i += 4) {
            int s0 = __shfl(sv, i),     s1 = __shfl(sv, i + 1);
            int s2 = __shfl(sv, i + 2), s3 = __shfl(sv, i + 3);
            float v0 = bf2f(Mpb[(size_t)s0 * 64 + lane]);
            float v1 = bf2f(Mpb[(size_t)s1 * 64 + lane]);
            float v2 = bf2f(Mpb[(size_t)s2 * 64 + lane]);
            float v3 = bf2f(Mpb[(size_t)s3 * 64 + lane]);
            acc += v0 + v1 + v2 + v3;
        }
        for (; i < n; ++i) {
            int s = __shfl(sv, i);
            acc += bf2f(Mpb[(size_t)s * 64 + lane]);
        }
    }
    part[wave * 64 + lane] = acc;
    __syncthreads();
    if (wave == 0) {
        float t = part[lane] + part[64 + lane] + part[128 + lane] + part[192 + lane];
        atomicAdd(&pos_agg[d * 64 + lane], t);
    }
}

// ---------------- fused: 3 position-update rounds + p2t message GEMM (row-local) ----------------
__global__ __launch_bounds__(256) void pos_rounds(const float* __restrict__ pos0,
                                                  const float* __restrict__ agg,   // raw sums
                                                  const int* __restrict__ cnt,
                                                  const float* __restrict__ upd_w, // 128x64
                                                  const float* __restrict__ upd_b,
                                                  const float* __restrict__ msg_w, // 64x64
                                                  const float* __restrict__ msg_b,
                                                  float* __restrict__ Mt)          // 320x64
{
    __shared__ float cur[4][64], nxt[4][64], aggw[4][64];
    int tid = threadIdx.x;
    int r = tid >> 6, j = tid & 63;
    int row = blockIdx.x * 4 + r;
    int c = cnt[row];
    float invc = 1.f / (float)(c < 1 ? 1 : c);
    float aw = 0.f;
    const float* ar = agg + row * 64;
#pragma unroll 8
    for (int k = 0; k < 64; ++k) aw += ar[k] * upd_w[(64 + k) * 64 + j];
    aggw[r][j] = aw * invc + upd_b[j];
    cur[r][j] = pos0[row * 64 + j];
    __syncthreads();
#pragma unroll 1
    for (int round = 0; round < 3; ++round) {
        float acc = aggw[r][j];
#pragma unroll 8
        for (int k = 0; k < 64; ++k) acc += cur[r][k] * upd_w[k * 64 + j];
        nxt[r][j] = fmaxf(acc, 0.f);
        __syncthreads();
        cur[r][j] = nxt[r][j];
        __syncthreads();
    }
    float acc = msg_b[j];
#pragma unroll 8
    for (int k = 0; k < 64; ++k) acc += cur[r][k] * msg_w[k * 64 + j];
    Mt[row * 64 + j] = fmaxf(acc, 0.f);
}

// ---------------- p2t team rounds + game head (single block) ----------------
__global__ __launch_bounds__(256) void p2t_head(
    const float* __restrict__ Mt,
    const int* __restrict__ p2t_edges,
    const float* __restrict__ upd_w, const float* __restrict__ upd_b,
    const int* __restrict__ team_indices,
    const float* __restrict__ team_table,
    const int* __restrict__ home_p, const int* __restrict__ away_p,
    const float* __restrict__ gp_w1, const float* __restrict__ gp_b1,
    const float* __restrict__ gp_w2, const float* __restrict__ gp_b2,
    const float* __restrict__ gp_w3, const float* __restrict__ gp_b3,
    float* __restrict__ out)
{
    __shared__ int   tcnt[NT];
    __shared__ int   tlist[NT * T2_CAP];
    __shared__ float aggbar[NT * 64];
    __shared__ float teamA[NT * 64];
    __shared__ float teamB[NT * 64];
    __shared__ float z1[128];
    __shared__ float z2[64];
    int tid = threadIdx.x;

    if (tid < NT) tcnt[tid] = 0;
    __syncthreads();
    for (int e = tid; e < EP2T; e += 256) {
        int s = p2t_edges[e], d = p2t_edges[EP2T + e];
        int p = atomicAdd(&tcnt[d], 1);
        if (p < T2_CAP) tlist[d * T2_CAP + p] = s;
    }
    __syncthreads();
    for (int i = tid; i < NT * 64; i += 256) {
        int d = i >> 6, c = i & 63;
        int cn = tcnt[d];
        int cl = cn > T2_CAP ? T2_CAP : cn;
        float acc = 0.f;
        for (int j = 0; j < cl; ++j) acc += Mt[tlist[d * T2_CAP + j] * 64 + c];
        float dv = cn < 1 ? 1.f : (float)cn;
        aggbar[i] = acc / dv;
        teamA[i] = team_table[team_indices[d] * 64 + c];
    }
    __syncthreads();

    float* tin = teamA; float* tout = teamB;
    for (int round = 0; round < 3; ++round) {
        for (int i = tid; i < NT * 64; i += 256) {
            int r = i >> 6, j = i & 63;
            float acc = upd_b[j];
            for (int k = 0; k < 64; ++k) acc += tin[r * 64 + k] * upd_w[k * 64 + j];
            for (int k = 0; k < 64; ++k) acc += aggbar[r * 64 + k] * upd_w[(64 + k) * 64 + j];
            tout[i] = fmaxf(acc, 0.f);
        }
        __syncthreads();
        float* tmp = tin; tin = tout; tout = tmp;
    }

    int home = home_p[0], away = away_p[0];
    if (tid < 128) {
        float acc = gp_b1[tid];
        for (int k = 0; k < 128; ++k) {
            float g = (k < 64) ? tin[home * 64 + k] : tin[away * 64 + (k - 64)];
            acc += g * gp_w1[k * 128 + tid];
        }
        z1[tid] = fmaxf(acc, 0.f);
    }
    __syncthreads();
    if (tid < 64) {
        float acc = gp_b2[tid];
        for (int k = 0; k < 128; ++k) acc += z1[k] * gp_w2[k * 64 + tid];
        z2[tid] = fmaxf(acc, 0.f);
    }
    __syncthreads();
    if (tid == 0) {
        float acc = gp_b3[0];
        for (int k = 0; k < 64; ++k) acc += z2[k] * gp_w3[k];
        out[0] = 1.f / (1.f + __expf(-acc));
    }
}

// ---------------- host launcher ----------------
extern "C" void kernel_launch(void* const* d_in, const int* in_sizes, int n_in,
                              void* d_out, int out_size, void* d_ws, size_t ws_size,
                              hipStream_t stream)
{
    const float* X        = (const float*)d_in[0];
    const int*   pos_idx  = (const int*)d_in[1];
    const int*   team_idx = (const int*)d_in[2];
    const int*   p2p      = (const int*)d_in[3];
    const int*   p2t      = (const int*)d_in[4];
    const int*   chem     = (const int*)d_in[5];
    const int*   home_p   = (const int*)d_in[6];
    const int*   away_p   = (const int*)d_in[7];
    const float* enc_w1   = (const float*)d_in[8];
    const float* enc_b1   = (const float*)d_in[9];
    const float* enc_w2   = (const float*)d_in[10];
    const float* enc_b2   = (const float*)d_in[11];
    const float* pos_tab  = (const float*)d_in[12];
    const float* team_tab = (const float*)d_in[13];
    const float* q_w = (const float*)d_in[14]; const float* q_b = (const float*)d_in[15];
    const float* k_w = (const float*)d_in[16]; const float* k_b = (const float*)d_in[17];
    const float* v_w = (const float*)d_in[18]; const float* v_b = (const float*)d_in[19];
    const float* p2p_msg_w = (const float*)d_in[20]; const float* p2p_msg_b = (const float*)d_in[21];
    const float* p2p_upd_w = (const float*)d_in[22]; const float* p2p_upd_b = (const float*)d_in[23];
    const float* p2t_msg_w = (const float*)d_in[24]; const float* p2t_msg_b = (const float*)d_in[25];
    const float* p2t_upd_w = (const float*)d_in[26]; const float* p2t_upd_b = (const float*)d_in[27];
    const float* gp_w1 = (const float*)d_in[28]; const float* gp_b1 = (const float*)d_in[29];
    const float* gp_w2 = (const float*)d_in[30]; const float* gp_b2 = (const float*)d_in[31];
    const float* gp_w3 = (const float*)d_in[32]; const float* gp_b3 = (const float*)d_in[33];
    float* out = (float*)d_out;

    // ---- workspace layout (bytes), peak ~209.4 MB ----
    char* ws = (char*)d_ws;
    int*      slist     = (int*)  (ws + 0);            // NP*32*4 = 25.6MB
    u16*      T         = (u16*)  (ws + 25600000);     // NP*64 bf16 = 25.6MB
    float*    emb       = (float*)(ws + 51200000);     // NP*64 fp32 = 51.2MB
    u16*      Qb        = (u16*)  (ws + 102400000);
    u16*      Kb        = (u16*)  (ws + 128000000);
    u16*      Vb        = (u16*)  (ws + 153600000);
    u16*      Mpb       = (u16*)  (ws + 179200000);
    int*      p2p_list  = (int*)  (ws + 204800000);    // 2.62MB
    int*      chem_cnt  = (int*)  (ws + 207421440);    // 800KB
    float*    Zd        = (float*)(ws + 208221440);    // 800KB
    int*      p2p_cnt   = (int*)  (ws + 209021440);
    float*    pos_agg   = (float*)(ws + 209022720);
    float*    posA      = (float*)(ws + 209104640);
    float*    Mt        = (float*)(ws + 209186560);
    float*    Zp        = (float*)(ws + 209268480);
    u16*      Wpack     = (u16*)  (ws + 209268496);    // 80KB transposed bf16 weights
    u16* W1t  = Wpack;
    u16* W2t  = Wpack + 16384;
    u16* Qt   = Wpack + 24576;
    u16* Kt   = Wpack + 28672;
    u16* Vt   = Wpack + 32768;
    u16* Msgt = Wpack + 36864;

    const int NB_NP = (NP + 255) / 256;

    hipLaunchKernelGGL(init_kernel, dim3(NB_NP), dim3(256), 0, stream,
                       chem_cnt, p2p_cnt, Zp, pos_idx, pos_tab, posA, pos_agg,
                       enc_w1, enc_w2, q_w, k_w, v_w, p2p_msg_w, Wpack);
    hipLaunchKernelGGL(chem_bucket, dim3(SC_GRID), dim3(256), 0, stream, chem, chem_cnt, slist);
    hipLaunchKernelGGL(mfma_enc, dim3(ENC_GRID), dim3(256), 0, stream,
                       X, W1t, W2t, Qt, Kt, Vt,
                       enc_b1, enc_b2, q_b, k_b, v_b,
                       emb, Qb, Kb, Vb);
    hipLaunchKernelGGL(chem_wsum, dim3(NP / 16), dim3(256), 0, stream,
                       Qb, Kb, Vb, chem_cnt, slist, T, Zd);
    hipLaunchKernelGGL(zred, dim3(256), dim3(256), 0, stream, Zd, Zp);
    hipLaunchKernelGGL(chem_fin_msg, dim3(NP / 64), dim3(256), 0, stream,
                       emb, T, Zp, Msgt, p2p_msg_b, Mpb);
    hipLaunchKernelGGL(p2p_bucket, dim3(PB_BLOCKS), dim3(256), 0, stream, p2p, p2p_cnt, p2p_list);
    hipLaunchKernelGGL(p2p_agg, dim3(NPOS * AGG_SPLIT), dim3(256), 0, stream,
                       Mpb, p2p_cnt, p2p_list, pos_agg);
    hipLaunchKernelGGL(pos_rounds, dim3(NPOS / 4), dim3(256), 0, stream,
                       posA, pos_agg, p2p_cnt, p2p_upd_w, p2p_upd_b,
                       p2t_msg_w, p2t_msg_b, Mt);
    hipLaunchKernelGGL(p2t_head, dim3(1), dim3(256), 0, stream,
                       Mt, p2t, p2t_upd_w, p2t_upd_b, team_idx, team_tab, home_p, away_p,
                       gp_w1, gp_b1, gp_w2, gp_b2, gp_w3, gp_b3, out);
}